// Round 14
// baseline (2185.754 us; speedup 1.0000x reference)
//
#include <hip/hip_runtime.h>
#include <hip/hip_bf16.h>

#define DIM 64
#define NC 50
#define TABN 4096
#define TABP (TABN + 2)   // rows 0..4096 = h at p*5/4096, row 4097 = mask row
#define EPB 4096          // edges per block in CSR build
#define NBMAX 512         // max buckets (N <= 65536)

typedef short bf16x8 __attribute__((ext_vector_type(8)));
typedef float f32x4  __attribute__((ext_vector_type(4)));
#define MFMA(a,b,c) __builtin_amdgcn_mfma_f32_16x16x32_bf16(a,b,c,0,0,0)

__device__ __forceinline__ float sp_f(float x){
  // torch Softplus(beta=0.5, threshold=14): 2*log(1+exp(0.5x)), linear when 0.5*x>14
  float e = __expf(0.5f*x);
  float s = 2.0f*__logf(1.0f+e);
  return x > 28.0f ? x : s;
}

__device__ __forceinline__ float rdl(float v, int l){
  return __int_as_float(__builtin_amdgcn_readlane(__float_as_int(v), l));
}

__device__ __forceinline__ unsigned short b16(float x){
  __hip_bfloat16 h = __float2bfloat16(x);
  return __builtin_bit_cast(unsigned short, h);
}

// split x into hi + lo bf16 (lo = bf16(x - float(hi))) -> ~fp32 via 3-term MFMA
__device__ __forceinline__ void wsplit(float x, unsigned short& h, unsigned short& l){
  h = b16(x);
  float hf = __uint_as_float(((unsigned int)h) << 16);
  l = b16(x - hf);
}

// ---------------- CSR build: bucket-grouping only (no within-bucket sort) -------

__global__ __launch_bounds__(256) void bhist_kernel(const int* __restrict__ dst,
                                                    unsigned int* __restrict__ gbcnt,
                                                    unsigned int* __restrict__ flagbits,
                                                    int E, int NB, int FW){
  __shared__ unsigned int cnt[NBMAX];
  int tid = threadIdx.x;
  for (int b=tid; b<NB; b+=256) cnt[b] = 0;
  __syncthreads();
  int e0 = blockIdx.x*EPB, eend = min(e0+EPB, E);
  for (int e=e0+tid; e<eend; e+=256) atomicAdd(&cnt[dst[e]>>7], 1u);
  for (int w = blockIdx.x*256+tid; w < FW; w += gridDim.x*256) flagbits[w] = 0;
  __syncthreads();
  for (int b=tid; b<NB; b+=256) if (cnt[b]) atomicAdd(&gbcnt[b], cnt[b]);
}

__global__ void sel_mark_kernel(const int* __restrict__ sel,
                                unsigned int* __restrict__ flagbits, int K){
  int id = blockIdx.x*256 + threadIdx.x;
  if (id < K){ int e = sel[id]; atomicOr(&flagbits[e>>5], 1u << (e&31)); }
}

__global__ __launch_bounds__(NBMAX) void bscan_kernel(const unsigned int* __restrict__ gbcnt,
                                                      unsigned int* __restrict__ bscan,
                                                      unsigned int* __restrict__ gcursor,
                                                      int NB){
  __shared__ unsigned int s[NBMAX];
  int tid = threadIdx.x;
  unsigned int v = (tid < NB) ? gbcnt[tid] : 0;
  s[tid] = v;
  __syncthreads();
  for (int off=1; off<NBMAX; off<<=1){
    unsigned int u = (tid >= off) ? s[tid-off] : 0;
    __syncthreads();
    s[tid] += u;
    __syncthreads();
  }
  unsigned int excl = s[tid] - v;
  if (tid < NB){ bscan[tid] = excl; gcursor[tid] = excl; }
  if (tid == NB-1) bscan[NB] = excl + v;
}

// bucket-scatter: 8B entries {dstloc(7b) | (src<<16)|tabidx} grouped by bucket
__global__ __launch_bounds__(256) void passA_kernel(const int* __restrict__ dst,
                                                    const int* __restrict__ src,
                                                    const float* __restrict__ dist,
                                                    const unsigned int* __restrict__ flagbits,
                                                    unsigned int* __restrict__ gcursor,
                                                    unsigned long long* __restrict__ bbuf,
                                                    int E, int NB){
  __shared__ unsigned int cnt[NBMAX];
  __shared__ unsigned int base[NBMAX];
  int tid = threadIdx.x;
  for (int b=tid; b<NB; b+=256) cnt[b] = 0;
  __syncthreads();
  int e0 = blockIdx.x*EPB, eend = min(e0+EPB, E);
  for (int e=e0+tid; e<eend; e+=256) atomicAdd(&cnt[dst[e]>>7], 1u);
  __syncthreads();
  for (int b=tid; b<NB; b+=256){
    unsigned int c = cnt[b];
    base[b] = c ? atomicAdd(&gcursor[b], c) : 0u;
    cnt[b] = 0;                       // reuse as local cursor
  }
  __syncthreads();
  for (int e=e0+tid; e<eend; e+=256){
    int d = dst[e];
    int b = d >> 7;
    unsigned int loc = atomicAdd(&cnt[b], 1u);
    float t = fminf(dist[e], 5.f) * ((float)TABN/5.0f);
    int idx = (int)(t + 0.5f); if (idx > TABN) idx = TABN;   // nearest grid point
    if ((flagbits[e>>5] >> (e&31)) & 1u) idx = TABN+1;       // mask row
    unsigned int lo = ((unsigned int)src[e] << 16) | (unsigned int)idx; // src<65536
    unsigned int hi = (unsigned int)(d & 127);
    bbuf[base[b] + loc] = ((unsigned long long)hi << 32) | lo;
  }
}

// ---------------- prep: transposes (table + heads) + split weight panels ----------

__global__ void prep_transpose_kernel(const float* __restrict__ cf_w2,
                                      const float* __restrict__ et1_w,
                                      const float* __restrict__ nt1_w,
                                      const float* __restrict__ cf_w1,
                                      float* __restrict__ w2t,
                                      float* __restrict__ et1t,
                                      float* __restrict__ nt1t,
                                      float* __restrict__ w1t){
  int id = blockIdx.x*256 + threadIdx.x;
  if (id < 3*4096){
    int i = id >> 12, r = id & 4095;
    int k = r >> 6, j = r & 63;
    w2t[id]  = cf_w2[i*4096 + j*64 + k];
  }
  if (id < 128*64){
    int k = id >> 6, j = id & 63;
    et1t[id] = et1_w[j*128 + k];   // et1_w is [64][128]
  }
  if (id < 64*32){
    int k = id >> 5, j = id & 31;
    nt1t[id] = nt1_w[j*64 + k];    // nt1_w is [32][64]
  }
  if (id < 3*NC*DIM){              // cf_w1 [3][64][50] -> w1t [3][50][64]
    int l = id / (NC*DIM);
    int r = id - l*(NC*DIM);
    int m = r >> 6, k = r & 63;
    w1t[id] = cf_w1[l*DIM*NC + k*NC + m];
  }
}

// split+swizzle 9 matrices -> global panels wpan[mat][4096] u32 (hi 2048, lo 2048)
// mat 0..2 = conv_w1[l]; 3..5 = nl2[l]; 6..8 = nl3[l]
__global__ void wprep_kernel(const float* __restrict__ cw1,
                             const float* __restrict__ nl2,
                             const float* __restrict__ nl3,
                             unsigned int* __restrict__ wpan){
  int id = blockIdx.x*256 + threadIdx.x;
  if (id >= 9*2048) return;
  int mat = id >> 11, i = id & 2047;
  const float* srcm = (mat < 3) ? (cw1 + mat*4096)
                    : (mat < 6) ? (nl2 + (mat-3)*4096)
                                : (nl3 + (mat-6)*4096);
  int row = i >> 5, cp = i & 31;
  float2 v = *(const float2*)(srcm + row*64 + cp*2);
  unsigned short hx,lx,hy,ly;
  wsplit(v.x, hx, lx);
  wsplit(v.y, hy, ly);
  int boff = row*128 + ((cp*4) ^ ((row&7)<<4));
  unsigned int* pan = wpan + mat*4096;
  pan[boff>>2]        = (unsigned int)hx | ((unsigned int)hy << 16);
  pan[2048 + (boff>>2)] = (unsigned int)lx | ((unsigned int)ly << 16);
}

// ---------------- filter table (bf16, nearest), wave = row, lane = feature ----------

__global__ __launch_bounds__(256) void table_kernel(const float* __restrict__ edge_mask,
                                                    const float* __restrict__ w1t,   // [3][50][64]
                                                    const float* __restrict__ cf_b1,
                                                    const float* __restrict__ w2t,   // [3][64][64]
                                                    const float* __restrict__ cf_b2,
                                                    __hip_bfloat16* __restrict__ tabb){
  int row = blockIdx.x*4 + (threadIdx.x >> 6);
  if (row >= 3*TABP) return;
  int l = row / TABP, p = row - l*TABP;
  int lane = threadIdx.x & 63;
  float rbfv = 0.f;
  if (lane < NC){
    if (p == TABN+1) rbfv = edge_mask[lane];
    else {
      float d = (float)p * (5.0f/(float)TABN);
      float c = (lane == NC-1) ? 5.0f : (float)((double)lane * (5.0/49.0));
      float df = d - c;
      rbfv = __expf((float)(-1.0/(5.0/49.0)) * df * df);
    }
  }
  const float* W1 = w1t + l*NC*DIM;
  float t = cf_b1[l*DIM + lane];
  #pragma unroll 10
  for (int m=0;m<NC;m++)
    t = fmaf(rdl(rbfv, m), W1[m*64 + lane], t);
  float su = sp_f(t);
  const float* W2 = w2t + l*DIM*DIM;
  float h = cf_b2[l*DIM + lane];
  #pragma unroll 16
  for (int k=0;k<DIM;k++)
    h = fmaf(rdl(su, k), W2[k*64 + lane], h);
  tabb[((size_t)l*TABP + p)*DIM + lane] = __float2bfloat16(h);
}

// ---------------- MFMA helpers (verified v6 fragment code) ----------------

__device__ __forceinline__ bf16x8 ldfrag(const char* base, int rowbase, int ks, int lane){
  int r = lane & 15;
  int off = (ks<<6) + ((lane>>4)<<4);
  return *(const bf16x8*)(base + (rowbase + r)*128 + (off ^ ((r & 7)<<4)));
}

__device__ __forceinline__ void stx(char* XH, char* XLo, int row, int col, float v){
  unsigned short h,l;
  wsplit(v, h, l);
  int off = row*128 + ((col*2) ^ ((row&7)<<4));
  *(unsigned short*)(XH + off) = h;
  *(unsigned short*)(XLo + off) = l;
}

#define MM6(WH_, WLo_, NT, ACC) \
  { ACC = MFMA(ah0, ldfrag(WH_,  (NT)*16, 0, lane), ACC); \
    ACC = MFMA(ah1, ldfrag(WH_,  (NT)*16, 1, lane), ACC); \
    ACC = MFMA(ah0, ldfrag(WLo_, (NT)*16, 0, lane), ACC); \
    ACC = MFMA(ah1, ldfrag(WLo_, (NT)*16, 1, lane), ACC); \
    ACC = MFMA(al0, ldfrag(WH_,  (NT)*16, 0, lane), ACC); \
    ACC = MFMA(al1, ldfrag(WH_,  (NT)*16, 1, lane), ACC); }

#define LDA(XH_, XLo_) \
  bf16x8 ah0 = ldfrag(XH_, mb, 0, lane), ah1 = ldfrag(XH_, mb, 1, lane); \
  bf16x8 al0 = ldfrag(XLo_, mb, 0, lane), al1 = ldfrag(XLo_, mb, 1, lane);

// node = emb[node_type]; nnb0 = bf16(node @ conv_w1[0]^T)   (panels from wprep)
__global__ __launch_bounds__(256) void node_init7_kernel(const float* __restrict__ emb,
                                                         const int* __restrict__ node_type,
                                                         const unsigned int* __restrict__ p0,
                                                         float* __restrict__ node,
                                                         unsigned short* __restrict__ nout, int N){
  __shared__ __align__(16) char WL[16384];
  __shared__ __align__(16) char XP[16384];
  char *WH = WL, *WLo = WL + 8192;
  char *XH = XP, *XLo = XP + 8192;
  int tid = threadIdx.x, lane = tid & 63, wv = tid >> 6;
  int nb = blockIdx.x*64, mb = wv*16;
  for (int i=tid; i<4096; i+=256) ((unsigned int*)WL)[i] = p0[i];
  #pragma unroll
  for (int t=0;t<16;t++){
    int row = mb + t, n = nb + row;
    int ty = (n < N) ? node_type[n] : 0;
    float v = emb[(long)ty*64 + lane];
    if (n < N) node[(long)n*64 + lane] = v;
    stx(XH, XLo, row, lane, v);
  }
  __syncthreads();
  LDA(XH, XLo)
  #pragma unroll
  for (int nt=0; nt<4; nt++){
    f32x4 acc = {0.f,0.f,0.f,0.f};
    MM6(WH, WLo, nt, acc)
    int col = nt*16 + (lane&15);
    #pragma unroll
    for (int v=0; v<4; v++){
      int n = nb + mb + ((lane>>4)<<2) + v;
      if (n < N) nout[(long)n*64 + col] = b16(acc[v]);
    }
  }
}

// ---------------- fused layer kernel: bucket agg (LDS ds_add) + MFMA update ------
// block = bucket of 128 dst-nodes, 512 threads (8 waves), 64KB static LDS.
// Phase A: waves stream bbuf entries of the bucket, gather tab/nnb rows,
//          atomicAdd into AGG[128][64] (lane->bank 2-way, free).
// Phase B: AGG -> split-bf16 X panels in place; 3-matmul MFMA chain (wave =
//          16-row strip); node(f32) += ..., nout = bf16(node_new @ cw1_next^T).

template<bool PRODUCE_NN>
__global__ __launch_bounds__(512) void layer_kernel(const unsigned long long* __restrict__ bbuf,
                                                    const unsigned int* __restrict__ bscan,
                                                    const unsigned short* __restrict__ tab,   // [TABP][64]
                                                    const unsigned short* __restrict__ nin,   // bf16 rows
                                                    const unsigned int* __restrict__ pA,      // nl2 panels
                                                    const unsigned int* __restrict__ pB,      // nl3 panels
                                                    const unsigned int* __restrict__ pC,      // cw1_next
                                                    const float* __restrict__ b2v,
                                                    const float* __restrict__ b3v,
                                                    float* __restrict__ node,
                                                    unsigned short* __restrict__ nout, int N){
  __shared__ __align__(16) char LDSM[65536];
  float* AGG = (float*)LDSM;                 // [128][64] f32 (32KB), becomes X panels
  char* XH  = LDSM;                          // 16KB
  char* XLo = LDSM + 16384;                  // 16KB
  char* WA  = LDSM + 32768;                  // hi 8K + lo 8K
  char* WB  = LDSM + 49152;                  // hi 8K + lo 8K
  int tid = threadIdx.x, lane = tid & 63, wv = tid >> 6;
  int b = blockIdx.x, nb0 = b << 7;
  // zero AGG + stage W panels
  #pragma unroll
  for (int j=0;j<16;j++) AGG[tid + 512*j] = 0.f;
  for (int i=tid; i<4096; i+=512){
    ((unsigned int*)WA)[i] = pA[i];
    ((unsigned int*)WB)[i] = pB[i];
  }
  __syncthreads();
  // -------- Phase A: gather-aggregate into LDS --------
  unsigned int s0 = bscan[b];
  int m = (int)(bscan[b+1] - s0);
  const unsigned long long* eb = bbuf + s0;
  for (int c = wv*64; c < m; c += 512){
    int rem = m - c; if (rem > 64) rem = 64;
    unsigned long long pk = eb[c + (lane < rem ? lane : 0)];
    unsigned int lo = (unsigned int)pk;
    unsigned int hi = (unsigned int)(pk >> 32);
    int q = 0;
    for (; q + 4 <= rem; q += 4){
      #pragma unroll
      for (int u=0; u<4; u++){
        unsigned int pl = (unsigned int)__builtin_amdgcn_readlane((int)lo, q+u);
        unsigned int ph = (unsigned int)__builtin_amdgcn_readlane((int)hi, q+u);
        int idx = pl & 0xFFFF, s = pl >> 16;
        float a  = __uint_as_float(((unsigned int)tab[idx*64 + lane]) << 16);
        float nn = __uint_as_float(((unsigned int)nin[(long)s*64 + lane]) << 16);
        atomicAdd(&AGG[(int)(ph & 127)*64 + lane], nn*a);
      }
    }
    for (; q < rem; q++){
      unsigned int pl = (unsigned int)__builtin_amdgcn_readlane((int)lo, q);
      unsigned int ph = (unsigned int)__builtin_amdgcn_readlane((int)hi, q);
      int idx = pl & 0xFFFF, s = pl >> 16;
      float a  = __uint_as_float(((unsigned int)tab[idx*64 + lane]) << 16);
      float nn = __uint_as_float(((unsigned int)nin[(long)s*64 + lane]) << 16);
      atomicAdd(&AGG[(int)(ph & 127)*64 + lane], nn*a);
    }
  }
  __syncthreads();
  // -------- convert AGG -> split X panels (in place) --------
  float av[16];
  #pragma unroll
  for (int j=0;j<16;j++) av[j] = AGG[tid + 512*j];
  __syncthreads();
  #pragma unroll
  for (int j=0;j<16;j++){
    int i = tid + 512*j;
    stx(XH, XLo, i >> 6, i & 63, av[j]);
  }
  __syncthreads();
  // -------- Phase B: MFMA chain (wave = 16-row strip) --------
  int mb = wv*16;
  // matmul1: S = sp(X @ nl2^T + b2) -> X panels (own rows)
  {
    LDA(XH, XLo)
    #pragma unroll
    for (int nt=0; nt<4; nt++){
      float bb = b2v[nt*16 + (lane&15)];
      f32x4 acc = {bb,bb,bb,bb};
      MM6(WA, WA+8192, nt, acc)
      int col = nt*16 + (lane&15);
      #pragma unroll
      for (int v=0; v<4; v++){
        int row = mb + ((lane>>4)<<2) + v;
        stx(XH, XLo, row, col, sp_f(acc[v]));
      }
    }
  }
  // matmul2: node_new = node + S @ nl3^T + b3 -> node(f32) + X panels
  {
    LDA(XH, XLo)
    #pragma unroll
    for (int nt=0; nt<4; nt++){
      float bb = b3v[nt*16 + (lane&15)];
      f32x4 acc = {bb,bb,bb,bb};
      MM6(WB, WB+8192, nt, acc)
      int col = nt*16 + (lane&15);
      #pragma unroll
      for (int v=0; v<4; v++){
        int row = mb + ((lane>>4)<<2) + v;
        int n = nb0 + row;
        float nv = 0.f;
        if (n < N){
          long g = (long)n*64 + col;
          nv = node[g] + acc[v];
          node[g] = nv;
        }
        stx(XH, XLo, row, col, nv);
      }
    }
  }
  if (PRODUCE_NN){
    __syncthreads();                 // all waves past matmul1/2 before WA overwrite
    for (int i=tid; i<4096; i+=512) ((unsigned int*)WA)[i] = pC[i];
    __syncthreads();
    LDA(XH, XLo)
    #pragma unroll
    for (int nt=0; nt<4; nt++){
      f32x4 acc = {0.f,0.f,0.f,0.f};
      MM6(WA, WA+8192, nt, acc)
      int col = nt*16 + (lane&15);
      #pragma unroll
      for (int v=0; v<4; v++){
        int n = nb0 + mb + ((lane>>4)<<2) + v;
        if (n < N) nout[(long)n*64 + col] = b16(acc[v]);
      }
    }
  }
}

// ---------------- heads ----------------

__global__ __launch_bounds__(256) void node_head_kernel(const float* __restrict__ node,
                                                        const int* __restrict__ nidx,
                                                        const float* __restrict__ nt1t,  // [64][32]
                                                        const float* __restrict__ nt1_b,
                                                        const float* __restrict__ nt2_w, // [3][32]
                                                        const float* __restrict__ nt2_b,
                                                        float* __restrict__ out, int NSEL){
  int r = __builtin_amdgcn_readfirstlane(blockIdx.x*4 + (threadIdx.x>>6));
  int lane = threadIdx.x & 63;
  if (r >= NSEL) return;
  long n = nidx[r];
  const float* x = node + n*64;                    // uniform -> s_loads
  float u = 0.f;
  if (lane < 32){
    u = nt1_b[lane];
    #pragma unroll
    for (int k=0;k<DIM;k++) u += x[k]*nt1t[k*32 + lane];
  }
  #pragma unroll
  for (int q=0;q<3;q++){
    float v = (lane < 32) ? u*nt2_w[q*32 + lane] : 0.f;
    #pragma unroll
    for (int o=32;o>=1;o>>=1) v += __shfl_xor(v, o);
    if (lane == 0) out[(long)r*3 + q] = nt2_b[q] + v;
  }
}

__global__ __launch_bounds__(256) void edge_head_kernel(const float* __restrict__ node,
                                                        const int* __restrict__ sidx,
                                                        const int* __restrict__ tidx,
                                                        const float* __restrict__ et1t, // [128][64]
                                                        const float* __restrict__ et1_b,
                                                        const float* __restrict__ et2_w,// [5][64]
                                                        const float* __restrict__ et2_b,
                                                        float* __restrict__ out, int ESEL){
  int wid = threadIdx.x >> 6, lane = threadIdx.x & 63;
  int r0 = (blockIdx.x*4 + wid)*4;
  if (r0 >= ESEL) return;
  float xs[4], xt[4], acc[4];
  #pragma unroll
  for (int i=0;i<4;i++){
    int r = r0+i < ESEL ? r0+i : ESEL-1;
    long s = sidx[r], t = tidx[r];
    xs[i] = node[s*64 + lane];
    xt[i] = node[t*64 + lane];
    acc[i] = et1_b[lane];
  }
  #pragma unroll 16
  for (int k=0;k<DIM;k++){
    float w1 = et1t[k*64 + lane];
    float w2 = et1t[(64+k)*64 + lane];
    #pragma unroll
    for (int i=0;i<4;i++){
      acc[i] = fmaf(rdl(xs[i], k), w1, acc[i]);
      acc[i] = fmaf(rdl(xt[i], k), w2, acc[i]);
    }
  }
  #pragma unroll
  for (int i=0;i<4;i++){
    if (r0+i >= ESEL) break;
    #pragma unroll
    for (int q=0;q<5;q++){
      float v = acc[i]*et2_w[q*64 + lane];
      #pragma unroll
      for (int o=32;o>=1;o>>=1) v += __shfl_xor(v, o);
      if (lane == 0) out[(long)(r0+i)*5 + q] = et2_b[q] + v;
    }
  }
}

// ---------------- launch ----------------

extern "C" void kernel_launch(void* const* d_in, const int* in_sizes, int n_in,
                              void* d_out, int out_size, void* d_ws, size_t ws_size,
                              hipStream_t stream){
  const float* emb      = (const float*)d_in[0];
  const float* dist     = (const float*)d_in[1];
  const float* edge_mask= (const float*)d_in[2];
  const float* conv_w1  = (const float*)d_in[3];
  const float* cf_w1    = (const float*)d_in[4];
  const float* cf_b1    = (const float*)d_in[5];
  const float* cf_w2    = (const float*)d_in[6];
  const float* cf_b2    = (const float*)d_in[7];
  const float* nl2_w    = (const float*)d_in[8];
  const float* nl2_b    = (const float*)d_in[9];
  const float* nl3_w    = (const float*)d_in[10];
  const float* nl3_b    = (const float*)d_in[11];
  const float* nt1_w    = (const float*)d_in[12];
  const float* nt1_b    = (const float*)d_in[13];
  const float* nt2_w    = (const float*)d_in[14];
  const float* nt2_b    = (const float*)d_in[15];
  const float* et1_w    = (const float*)d_in[16];
  const float* et1_b    = (const float*)d_in[17];
  const float* et2_w    = (const float*)d_in[18];
  const float* et2_b    = (const float*)d_in[19];
  const int* node_type  = (const int*)d_in[20];
  const int* src        = (const int*)d_in[21];
  const int* dst        = (const int*)d_in[22];
  const int* sel        = (const int*)d_in[23];
  const int* node_index = (const int*)d_in[24];
  const int* source_index = (const int*)d_in[25];
  const int* target_index = (const int*)d_in[26];

  int E    = in_sizes[1];
  int N    = in_sizes[20];
  int K    = in_sizes[23];
  int NSEL = in_sizes[24];
  int ESEL = in_sizes[25];

  int NB  = (N + 127) >> 7;           // buckets of 128 nodes
  int FW  = (E + 31) >> 5;            // flag words
  int nbE = (E + EPB - 1) / EPB;      // CSR-build blocks

  size_t N64 = (size_t)N*64;
  unsigned long long* bbuf = (unsigned long long*)d_ws;   // persists all 3 layers
  float* p = (float*)d_ws + 2*(size_t)E;
  float* node     = p; p += N64;
  unsigned short* nnbA = (unsigned short*)p; p += N64/2;  // bf16 new_node, buffer A
  unsigned short* nnbB = (unsigned short*)p; p += N64/2;  // buffer B
  float* w2t      = p; p += 3*4096;
  float* et1t     = p; p += 128*64;
  float* nt1t     = p; p += 64*32;
  float* w1t      = p; p += 3*NC*DIM;
  unsigned int* wpan = (unsigned int*)p; p += 9*4096;     // split weight panels
  __hip_bfloat16* tabb = (__hip_bfloat16*)p; p += (size_t)3*TABP*DIM/2;
  unsigned int* flagbits = (unsigned int*)p; p += FW;
  unsigned int* gbcnt    = (unsigned int*)p; p += NB;
  unsigned int* bscan    = (unsigned int*)p; p += NB+1;
  unsigned int* gcursor  = (unsigned int*)p; p += NB;

  // CSR build (bucket-grouping only)
  hipMemsetAsync(gbcnt, 0, (size_t)NB*sizeof(int), stream);
  bhist_kernel<<<nbE, 256, 0, stream>>>(dst, gbcnt, flagbits, E, NB, FW);
  sel_mark_kernel<<<(K+255)/256, 256, 0, stream>>>(sel, flagbits, K);
  prep_transpose_kernel<<<48, 256, 0, stream>>>(cf_w2, et1_w, nt1_w, cf_w1,
                                                w2t, et1t, nt1t, w1t);
  wprep_kernel<<<72, 256, 0, stream>>>(conv_w1, nl2_w, nl3_w, wpan);
  bscan_kernel<<<1, NBMAX, 0, stream>>>(gbcnt, bscan, gcursor, NB);
  passA_kernel<<<nbE, 256, 0, stream>>>(dst, src, dist, flagbits, gcursor, bbuf, E, NB);
  // filter tables
  table_kernel<<<(3*TABP+3)/4, 256, 0, stream>>>(edge_mask, w1t, cf_b1, w2t, cf_b2, tabb);

  node_init7_kernel<<<(N+63)/64, 256, 0, stream>>>(emb, node_type, wpan, node, nnbA, N);

  for (int l=0;l<3;l++){
    const unsigned short* tab_l = (const unsigned short*)(tabb + (size_t)l*TABP*DIM);
    const unsigned short* nin  = (l & 1) ? nnbB : nnbA;
    unsigned short* nout       = (l & 1) ? nnbA : nnbB;
    const unsigned int* pA = wpan + (3+l)*4096;
    const unsigned int* pB = wpan + (6+l)*4096;
    if (l < 2)
      layer_kernel<true><<<NB, 512, 0, stream>>>(bbuf, bscan, tab_l, nin,
          pA, pB, wpan + (l+1)*4096, nl2_b + l*64, nl3_b + l*64, node, nout, N);
    else
      layer_kernel<false><<<NB, 512, 0, stream>>>(bbuf, bscan, tab_l, nin,
          pA, pB, nullptr, nl2_b + l*64, nl3_b + l*64, node, nout, N);
  }

  node_head_kernel<<<(NSEL+3)/4, 256, 0, stream>>>(node, node_index,
      nt1t, nt1_b, nt2_w, nt2_b, (float*)d_out, NSEL);
  edge_head_kernel<<<(ESEL+15)/16, 256, 0, stream>>>(node, source_index, target_index,
      et1t, et1_b, et2_w, et2_b, (float*)d_out + (size_t)NSEL*3, ESEL);
}

// Round 15
// 329.345 us; speedup vs baseline: 6.6367x; 6.6367x over previous
//
#include <hip/hip_runtime.h>
#include <hip/hip_bf16.h>

#define DIM 64
#define NC 50
#define TABN 4096
#define TABP (TABN + 2)   // rows 0..4096 = h at p*5/4096, row 4097 = mask row
#define EPB 2048          // edges per block in CSR build
#define NBMAX 512         // max buckets (N <= 65536)

typedef short bf16x8 __attribute__((ext_vector_type(8)));
typedef float f32x4  __attribute__((ext_vector_type(4)));
#define MFMA(a,b,c) __builtin_amdgcn_mfma_f32_16x16x32_bf16(a,b,c,0,0,0)

__device__ __forceinline__ float sp_f(float x){
  // torch Softplus(beta=0.5, threshold=14): 2*log(1+exp(0.5x)), linear when 0.5*x>14
  float e = __expf(0.5f*x);
  float s = 2.0f*__logf(1.0f+e);
  return x > 28.0f ? x : s;
}

__device__ __forceinline__ float rdl(float v, int l){
  return __int_as_float(__builtin_amdgcn_readlane(__float_as_int(v), l));
}

__device__ __forceinline__ unsigned short b16(float x){
  __hip_bfloat16 h = __float2bfloat16(x);
  return __builtin_bit_cast(unsigned short, h);
}

// split x into hi + lo bf16 (lo = bf16(x - float(hi))) -> ~fp32 via 3-term MFMA
__device__ __forceinline__ void wsplit(float x, unsigned short& h, unsigned short& l){
  h = b16(x);
  float hf = __uint_as_float(((unsigned int)h) << 16);
  l = b16(x - hf);
}

// ---------------- CSR build: two-level LDS counting sort ----------------

__global__ __launch_bounds__(256) void bhist_kernel(const int* __restrict__ dst,
                                                    unsigned int* __restrict__ gbcnt,
                                                    unsigned int* __restrict__ flagbits,
                                                    int E, int NB, int FW){
  __shared__ unsigned int cnt[NBMAX];
  int tid = threadIdx.x;
  for (int b=tid; b<NB; b+=256) cnt[b] = 0;
  __syncthreads();
  int e0 = blockIdx.x*EPB, eend = min(e0+EPB, E);
  for (int e=e0+tid; e<eend; e+=256) atomicAdd(&cnt[dst[e]>>7], 1u);
  for (int w = blockIdx.x*256+tid; w < FW; w += gridDim.x*256) flagbits[w] = 0;
  __syncthreads();
  for (int b=tid; b<NB; b+=256) if (cnt[b]) atomicAdd(&gbcnt[b], cnt[b]);
}

__global__ void sel_mark_kernel(const int* __restrict__ sel,
                                unsigned int* __restrict__ flagbits, int K){
  int id = blockIdx.x*256 + threadIdx.x;
  if (id < K){ int e = sel[id]; atomicOr(&flagbits[e>>5], 1u << (e&31)); }
}

__global__ __launch_bounds__(NBMAX) void bscan_kernel(const unsigned int* __restrict__ gbcnt,
                                                      unsigned int* __restrict__ bscan,
                                                      unsigned int* __restrict__ gcursor,
                                                      int* __restrict__ offs,
                                                      int NB, int N, int E){
  __shared__ unsigned int s[NBMAX];
  int tid = threadIdx.x;
  unsigned int v = (tid < NB) ? gbcnt[tid] : 0;
  s[tid] = v;
  __syncthreads();
  for (int off=1; off<NBMAX; off<<=1){
    unsigned int u = (tid >= off) ? s[tid-off] : 0;
    __syncthreads();
    s[tid] += u;
    __syncthreads();
  }
  unsigned int excl = s[tid] - v;
  if (tid < NB){ bscan[tid] = excl; gcursor[tid] = excl; }
  if (tid == NB-1) bscan[NB] = excl + v;
  if (tid == 0) offs[N] = E;
}

__global__ __launch_bounds__(256) void passA_kernel(const int* __restrict__ dst,
                                                    const int* __restrict__ src,
                                                    const float* __restrict__ dist,
                                                    const unsigned int* __restrict__ flagbits,
                                                    unsigned int* __restrict__ gcursor,
                                                    unsigned long long* __restrict__ bbuf,
                                                    int E, int NB){
  __shared__ unsigned int cnt[NBMAX];
  __shared__ unsigned int base[NBMAX];
  int tid = threadIdx.x;
  for (int b=tid; b<NB; b+=256) cnt[b] = 0;
  __syncthreads();
  int e0 = blockIdx.x*EPB, eend = min(e0+EPB, E);
  for (int e=e0+tid; e<eend; e+=256) atomicAdd(&cnt[dst[e]>>7], 1u);
  __syncthreads();
  for (int b=tid; b<NB; b+=256){
    unsigned int c = cnt[b];
    base[b] = c ? atomicAdd(&gcursor[b], c) : 0u;
    cnt[b] = 0;                       // reuse as local cursor
  }
  __syncthreads();
  for (int e=e0+tid; e<eend; e+=256){
    int d = dst[e];
    int b = d >> 7;
    unsigned int loc = atomicAdd(&cnt[b], 1u);
    float t = fminf(dist[e], 5.f) * ((float)TABN/5.0f);
    int idx = (int)(t + 0.5f); if (idx > TABN) idx = TABN;   // nearest grid point
    if ((flagbits[e>>5] >> (e&31)) & 1u) idx = TABN+1;       // mask row
    unsigned int lo = ((unsigned int)src[e] << 16) | (unsigned int)idx; // src<65536
    unsigned int hi = (unsigned int)(d & 127);
    bbuf[base[b] + loc] = ((unsigned long long)hi << 32) | lo;
  }
}

__global__ __launch_bounds__(256) void passB_kernel(const unsigned long long* __restrict__ bbuf,
                                                    const unsigned int* __restrict__ bscan,
                                                    int* __restrict__ offs,
                                                    unsigned int* __restrict__ csr,
                                                    int N){
  __shared__ unsigned int cnt[128];
  __shared__ unsigned int excl[128];
  int b = blockIdx.x, tid = threadIdx.x;
  unsigned int s0 = bscan[b];
  int m = (int)(bscan[b+1] - s0);
  if (tid < 128) cnt[tid] = 0;
  __syncthreads();
  for (int i=tid; i<m; i+=256)
    atomicAdd(&cnt[(unsigned int)(bbuf[s0+i] >> 32)], 1u);
  __syncthreads();
  if (tid < 128) excl[tid] = cnt[tid];
  __syncthreads();
  for (int off=1; off<128; off<<=1){
    unsigned int v = (tid < 128 && tid >= off) ? excl[tid-off] : 0;
    __syncthreads();
    if (tid < 128) excl[tid] += v;
    __syncthreads();
  }
  int node0 = b << 7;
  if (tid < 128){
    unsigned int ex = excl[tid] - cnt[tid];    // exclusive
    int n = node0 + tid;
    if (n < N) offs[n] = (int)(s0 + ex);
    excl[tid] = ex;
    cnt[tid] = 0;                              // reuse as cursor
  }
  __syncthreads();
  for (int i=tid; i<m; i+=256){
    unsigned long long v = bbuf[s0+i];
    unsigned int hi = (unsigned int)(v >> 32);
    unsigned int loc = atomicAdd(&cnt[hi], 1u);
    csr[s0 + excl[hi] + loc] = (unsigned int)v;
  }
}

// ---------------- prep: weight transposes (table + heads only) ----------------

__global__ void prep_transpose_kernel(const float* __restrict__ cf_w2,
                                      const float* __restrict__ et1_w,
                                      const float* __restrict__ nt1_w,
                                      const float* __restrict__ cf_w1,
                                      float* __restrict__ w2t,
                                      float* __restrict__ et1t,
                                      float* __restrict__ nt1t,
                                      float* __restrict__ w1t){
  int id = blockIdx.x*256 + threadIdx.x;
  if (id < 3*4096){
    int i = id >> 12, r = id & 4095;
    int k = r >> 6, j = r & 63;
    w2t[id]  = cf_w2[i*4096 + j*64 + k];
  }
  if (id < 128*64){
    int k = id >> 6, j = id & 63;
    et1t[id] = et1_w[j*128 + k];   // et1_w is [64][128]
  }
  if (id < 64*32){
    int k = id >> 5, j = id & 31;
    nt1t[id] = nt1_w[j*64 + k];    // nt1_w is [32][64]
  }
  if (id < 3*NC*DIM){              // cf_w1 [3][64][50] -> w1t [3][50][64]
    int l = id / (NC*DIM);
    int r = id - l*(NC*DIM);
    int m = r >> 6, k = r & 63;
    w1t[id] = cf_w1[l*DIM*NC + k*NC + m];
  }
}

// ---------------- weight fragment tables (one-time; L2-hot, 144KB) ----------------
// For each matrix m (0..2 conv_w1[l], 3..5 nl2[l], 6..8 nl3[l]) precompute the
// exact per-lane MFMA B-fragment: fid = m*16 + nt*4 + ks*2 + part(hi/lo);
// wfrag[fid*64 + lane] = bf16x8 of W[nt*16+(lane&15)][ks*32+(lane>>4)*8 .. +7].
// A wave's fragment load is then ONE coalesced 1KB global_load_dwordx4 row.

__global__ void wprep2_kernel(const float* __restrict__ cw1,
                              const float* __restrict__ nl2,
                              const float* __restrict__ nl3,
                              bf16x8* __restrict__ wfrag){
  int id = blockIdx.x*256 + threadIdx.x;     // 9*8*64 = 4608 units
  if (id >= 9*8*64) return;
  int lane = id & 63;
  int f8 = (id >> 6) & 7;                    // nt*2 + ks
  int m  = id >> 9;
  int nt = f8 >> 1, ks = f8 & 1;
  const float* W = (m < 3) ? (cw1 + m*4096)
                 : (m < 6) ? (nl2 + (m-3)*4096)
                           : (nl3 + (m-6)*4096);
  int j  = nt*16 + (lane & 15);
  int k0 = ks*32 + (lane >> 4)*8;
  bf16x8 vh, vl;
  #pragma unroll
  for (int u=0;u<8;u++){
    unsigned short h,l;
    wsplit(W[j*64 + k0 + u], h, l);
    vh[u] = (short)h; vl[u] = (short)l;
  }
  int fb = m*16 + nt*4 + ks*2;
  wfrag[(fb+0)*64 + lane] = vh;
  wfrag[(fb+1)*64 + lane] = vl;
}

// ---------------- filter table (bf16, nearest), wave = row, lane = feature ----------

__global__ __launch_bounds__(256) void table_kernel(const float* __restrict__ edge_mask,
                                                    const float* __restrict__ w1t,   // [3][50][64]
                                                    const float* __restrict__ cf_b1,
                                                    const float* __restrict__ w2t,   // [3][64][64]
                                                    const float* __restrict__ cf_b2,
                                                    __hip_bfloat16* __restrict__ tabb){
  int row = blockIdx.x*4 + (threadIdx.x >> 6);
  if (row >= 3*TABP) return;
  int l = row / TABP, p = row - l*TABP;
  int lane = threadIdx.x & 63;
  float rbfv = 0.f;
  if (lane < NC){
    if (p == TABN+1) rbfv = edge_mask[lane];
    else {
      float d = (float)p * (5.0f/(float)TABN);
      float c = (lane == NC-1) ? 5.0f : (float)((double)lane * (5.0/49.0));
      float df = d - c;
      rbfv = __expf((float)(-1.0/(5.0/49.0)) * df * df);
    }
  }
  const float* W1 = w1t + l*NC*DIM;
  float t = cf_b1[l*DIM + lane];
  #pragma unroll 10
  for (int m=0;m<NC;m++)
    t = fmaf(rdl(rbfv, m), W1[m*64 + lane], t);
  float su = sp_f(t);
  const float* W2 = w2t + l*DIM*DIM;
  float h = cf_b2[l*DIM + lane];
  #pragma unroll 16
  for (int k=0;k<DIM;k++)
    h = fmaf(rdl(su, k), W2[k*64 + lane], h);
  tabb[((size_t)l*TABP + p)*DIM + lane] = __float2bfloat16(h);
}

// ---------------- node-side v8: MFMA, weights from global fragment tables --------
// Block = 64 nodes, 4 waves; wave = 16-row M-strip. Activations in 16KB swizzled
// split-bf16 LDS panels (A-operand); weights read as coalesced 1KB global rows
// (B-operand, L2-hot) -> no weight LDS, no per-block split/swizzle work.
// C/D: D[row=(l>>4)*4+reg][col=(l&15)]  [learn_hip m89/m91]

__device__ __forceinline__ bf16x8 ldfrag(const char* base, int rowbase, int ks, int lane){
  int r = lane & 15;
  int off = (ks<<6) + ((lane>>4)<<4);
  return *(const bf16x8*)(base + (rowbase + r)*128 + (off ^ ((r & 7)<<4)));
}

__device__ __forceinline__ void stx(char* XH, char* XLo, int row, int col, float v){
  unsigned short h,l;
  wsplit(v, h, l);
  int off = row*128 + ((col*2) ^ ((row&7)<<4));
  *(unsigned short*)(XH + off) = h;
  *(unsigned short*)(XLo + off) = l;
}

// 6-term split-precision product; WF = &wfrag[m*16*64], fragment ids per quadrant:
// nt*4 + {0: ks0 hi, 1: ks0 lo, 2: ks1 hi, 3: ks1 lo}
#define MM6G(WF, NT, ACC) \
  { ACC = MFMA(ah0, (WF)[((NT)*4+0)*64 + lane], ACC); \
    ACC = MFMA(ah1, (WF)[((NT)*4+2)*64 + lane], ACC); \
    ACC = MFMA(ah0, (WF)[((NT)*4+1)*64 + lane], ACC); \
    ACC = MFMA(ah1, (WF)[((NT)*4+3)*64 + lane], ACC); \
    ACC = MFMA(al0, (WF)[((NT)*4+0)*64 + lane], ACC); \
    ACC = MFMA(al1, (WF)[((NT)*4+2)*64 + lane], ACC); }

#define LDA(XH_, XLo_) \
  bf16x8 ah0 = ldfrag(XH_, mb, 0, lane), ah1 = ldfrag(XH_, mb, 1, lane); \
  bf16x8 al0 = ldfrag(XLo_, mb, 0, lane), al1 = ldfrag(XLo_, mb, 1, lane);

// node = emb[node_type]; nnb = bf16(node @ conv_w1[0]^T)
__global__ __launch_bounds__(256) void node_init8_kernel(const float* __restrict__ emb,
                                                         const int* __restrict__ node_type,
                                                         const bf16x8* __restrict__ wf0,
                                                         float* __restrict__ node,
                                                         unsigned short* __restrict__ nout, int N){
  __shared__ __align__(16) char XP[16384];
  char *XH = XP, *XLo = XP + 8192;
  int tid = threadIdx.x, lane = tid & 63, wv = tid >> 6;
  int nb = blockIdx.x*64, mb = wv*16;
  #pragma unroll
  for (int t=0;t<16;t++){
    int row = mb + t, n = nb + row;
    int ty = (n < N) ? node_type[n] : 0;
    float v = emb[(long)ty*64 + lane];
    if (n < N) node[(long)n*64 + lane] = v;
    stx(XH, XLo, row, lane, v);
  }
  __syncthreads();
  LDA(XH, XLo)
  #pragma unroll
  for (int nt=0; nt<4; nt++){
    f32x4 acc = {0.f,0.f,0.f,0.f};
    MM6G(wf0, nt, acc)
    int col = nt*16 + (lane&15);
    #pragma unroll
    for (int v=0; v<4; v++){
      int n = nb + mb + ((lane>>4)<<2) + v;
      if (n < N) nout[(long)n*64 + col] = b16(acc[v]);
    }
  }
}

// node += sp(agg@nl2^T+b2)@nl3^T+b3; optionally nnb = bf16(node_new @ cw1_next^T)
template<bool PRODUCE_NN>
__global__ __launch_bounds__(256) void node_update8_kernel(float* __restrict__ node,
                                                           const float* __restrict__ agg,
                                                           const bf16x8* __restrict__ wfA, // nl2 frags
                                                           const float* __restrict__ nl2_b,
                                                           const bf16x8* __restrict__ wfB, // nl3 frags
                                                           const float* __restrict__ nl3_b,
                                                           const bf16x8* __restrict__ wfC, // cw1_next
                                                           unsigned short* __restrict__ nout, int N){
  __shared__ __align__(16) char XP[16384];
  char *XH = XP, *XLo = XP + 8192;
  int tid = threadIdx.x, lane = tid & 63, wv = tid >> 6;
  int nb = blockIdx.x*64, mb = wv*16;
  // stage agg rows (wave-local)
  #pragma unroll
  for (int t=0;t<16;t++){
    int row = mb + t, n = nb + row;
    float v = (n < N) ? agg[(long)n*64 + lane] : 0.f;
    stx(XH, XLo, row, lane, v);
  }
  __syncthreads();
  // matmul1: S = sp(X @ nl2^T + b2) -> back into X panels (own rows)
  {
    LDA(XH, XLo)
    #pragma unroll
    for (int nt=0; nt<4; nt++){
      float bb = nl2_b[nt*16 + (lane&15)];
      f32x4 acc = {bb,bb,bb,bb};
      MM6G(wfA, nt, acc)
      int col = nt*16 + (lane&15);
      #pragma unroll
      for (int v=0; v<4; v++){
        int row = mb + ((lane>>4)<<2) + v;
        stx(XH, XLo, row, col, sp_f(acc[v]));
      }
    }
  }
  // matmul2: node_new = node + S @ nl3^T + b3 -> node (f32) and X panels
  {
    LDA(XH, XLo)
    #pragma unroll
    for (int nt=0; nt<4; nt++){
      float bb = nl3_b[nt*16 + (lane&15)];
      f32x4 acc = {bb,bb,bb,bb};
      MM6G(wfB, nt, acc)
      int col = nt*16 + (lane&15);
      #pragma unroll
      for (int v=0; v<4; v++){
        int row = mb + ((lane>>4)<<2) + v;
        int n = nb + row;
        float nv = 0.f;
        if (n < N){
          long g = (long)n*64 + col;
          nv = node[g] + acc[v];
          node[g] = nv;
        }
        stx(XH, XLo, row, col, nv);
      }
    }
  }
  if (PRODUCE_NN){
    LDA(XH, XLo)
    #pragma unroll
    for (int nt=0; nt<4; nt++){
      f32x4 acc = {0.f,0.f,0.f,0.f};
      MM6G(wfC, nt, acc)
      int col = nt*16 + (lane&15);
      #pragma unroll
      for (int v=0; v<4; v++){
        int n = nb + mb + ((lane>>4)<<2) + v;
        if (n < N) nout[(long)n*64 + col] = b16(acc[v]);
      }
    }
  }
}

// gather-aggregate: wave = 1 dst node, lane = feature; 4B csr, bf16 table + new_node
__global__ __launch_bounds__(256) void agg_kernel(const unsigned int* __restrict__ csr,
                                                  const int* __restrict__ offs,
                                                  const unsigned short* __restrict__ tab,  // [TABP][64] bf16
                                                  const unsigned short* __restrict__ nnb,  // bf16 bits
                                                  float* __restrict__ agg, int N){
  int n = blockIdx.x*4 + (threadIdx.x >> 6);
  int lane = threadIdx.x & 63;
  if (n >= N) return;
  int beg = offs[n], end = offs[n+1];
  float acc = 0.f;
  for (int c = beg; c < end; c += 64){
    int m = end - c; if (m > 64) m = 64;
    unsigned int pkv = csr[c + (lane < m ? lane : 0)];   // coalesced edge-list load
    int q = 0;
    for (; q + 8 <= m; q += 8){
      #pragma unroll
      for (int u=0; u<8; u++){
        unsigned int p = (unsigned int)__builtin_amdgcn_readlane((int)pkv, q+u); // SGPR
        int idx = p & 0xFFFF, s = p >> 16;
        float a  = __uint_as_float(((unsigned int)tab[idx*64 + lane]) << 16);
        float nn = __uint_as_float(((unsigned int)nnb[(long)s*64 + lane]) << 16);
        acc = fmaf(nn, a, acc);
      }
    }
    for (; q < m; q++){
      unsigned int p = (unsigned int)__builtin_amdgcn_readlane((int)pkv, q);
      int idx = p & 0xFFFF, s = p >> 16;
      float a  = __uint_as_float(((unsigned int)tab[idx*64 + lane]) << 16);
      float nn = __uint_as_float(((unsigned int)nnb[(long)s*64 + lane]) << 16);
      acc = fmaf(nn, a, acc);
    }
  }
  agg[(long)n*64 + lane] = acc;
}

// ---------------- heads ----------------

__global__ __launch_bounds__(256) void node_head_kernel(const float* __restrict__ node,
                                                        const int* __restrict__ nidx,
                                                        const float* __restrict__ nt1t,  // [64][32]
                                                        const float* __restrict__ nt1_b,
                                                        const float* __restrict__ nt2_w, // [3][32]
                                                        const float* __restrict__ nt2_b,
                                                        float* __restrict__ out, int NSEL){
  int r = __builtin_amdgcn_readfirstlane(blockIdx.x*4 + (threadIdx.x>>6));
  int lane = threadIdx.x & 63;
  if (r >= NSEL) return;
  long n = nidx[r];
  const float* x = node + n*64;                    // uniform -> s_loads
  float u = 0.f;
  if (lane < 32){
    u = nt1_b[lane];
    #pragma unroll
    for (int k=0;k<DIM;k++) u += x[k]*nt1t[k*32 + lane];
  }
  #pragma unroll
  for (int q=0;q<3;q++){
    float v = (lane < 32) ? u*nt2_w[q*32 + lane] : 0.f;
    #pragma unroll
    for (int o=32;o>=1;o>>=1) v += __shfl_xor(v, o);
    if (lane == 0) out[(long)r*3 + q] = nt2_b[q] + v;
  }
}

__global__ __launch_bounds__(256) void edge_head_kernel(const float* __restrict__ node,
                                                        const int* __restrict__ sidx,
                                                        const int* __restrict__ tidx,
                                                        const float* __restrict__ et1t, // [128][64]
                                                        const float* __restrict__ et1_b,
                                                        const float* __restrict__ et2_w,// [5][64]
                                                        const float* __restrict__ et2_b,
                                                        float* __restrict__ out, int ESEL){
  int wid = threadIdx.x >> 6, lane = threadIdx.x & 63;
  int r0 = (blockIdx.x*4 + wid)*4;
  if (r0 >= ESEL) return;
  float xs[4], xt[4], acc[4];
  #pragma unroll
  for (int i=0;i<4;i++){
    int r = r0+i < ESEL ? r0+i : ESEL-1;
    long s = sidx[r], t = tidx[r];
    xs[i] = node[s*64 + lane];
    xt[i] = node[t*64 + lane];
    acc[i] = et1_b[lane];
  }
  #pragma unroll 16
  for (int k=0;k<DIM;k++){
    float w1 = et1t[k*64 + lane];
    float w2 = et1t[(64+k)*64 + lane];
    #pragma unroll
    for (int i=0;i<4;i++){
      acc[i] = fmaf(rdl(xs[i], k), w1, acc[i]);
      acc[i] = fmaf(rdl(xt[i], k), w2, acc[i]);
    }
  }
  #pragma unroll
  for (int i=0;i<4;i++){
    if (r0+i >= ESEL) break;
    #pragma unroll
    for (int q=0;q<5;q++){
      float v = acc[i]*et2_w[q*64 + lane];
      #pragma unroll
      for (int o=32;o>=1;o>>=1) v += __shfl_xor(v, o);
      if (lane == 0) out[(long)(r0+i)*5 + q] = et2_b[q] + v;
    }
  }
}

// ---------------- launch ----------------

extern "C" void kernel_launch(void* const* d_in, const int* in_sizes, int n_in,
                              void* d_out, int out_size, void* d_ws, size_t ws_size,
                              hipStream_t stream){
  const float* emb      = (const float*)d_in[0];
  const float* dist     = (const float*)d_in[1];
  const float* edge_mask= (const float*)d_in[2];
  const float* conv_w1  = (const float*)d_in[3];
  const float* cf_w1    = (const float*)d_in[4];
  const float* cf_b1    = (const float*)d_in[5];
  const float* cf_w2    = (const float*)d_in[6];
  const float* cf_b2    = (const float*)d_in[7];
  const float* nl2_w    = (const float*)d_in[8];
  const float* nl2_b    = (const float*)d_in[9];
  const float* nl3_w    = (const float*)d_in[10];
  const float* nl3_b    = (const float*)d_in[11];
  const float* nt1_w    = (const float*)d_in[12];
  const float* nt1_b    = (const float*)d_in[13];
  const float* nt2_w    = (const float*)d_in[14];
  const float* nt2_b    = (const float*)d_in[15];
  const float* et1_w    = (const float*)d_in[16];
  const float* et1_b    = (const float*)d_in[17];
  const float* et2_w    = (const float*)d_in[18];
  const float* et2_b    = (const float*)d_in[19];
  const int* node_type  = (const int*)d_in[20];
  const int* src        = (const int*)d_in[21];
  const int* dst        = (const int*)d_in[22];
  const int* sel        = (const int*)d_in[23];
  const int* node_index = (const int*)d_in[24];
  const int* source_index = (const int*)d_in[25];
  const int* target_index = (const int*)d_in[26];

  int E    = in_sizes[1];
  int N    = in_sizes[20];
  int K    = in_sizes[23];
  int NSEL = in_sizes[24];
  int ESEL = in_sizes[25];

  int NB  = (N + 127) >> 7;           // buckets of 128 nodes
  int FW  = (E + 31) >> 5;            // flag words
  int nbE = (E + EPB - 1) / EPB;      // CSR-build blocks

  size_t N64 = (size_t)N*64;
  // bbuf (E u64) first for 8B alignment; agg aliases it (lifetimes disjoint)
  unsigned long long* bbuf = (unsigned long long*)d_ws;
  float* agg = (float*)d_ws;
  size_t aggsz = ((size_t)2*E > N64) ? (size_t)2*E : N64;   // float units
  float* p = (float*)d_ws + aggsz;
  float* node     = p; p += N64;
  unsigned short* nnb = (unsigned short*)p; p += N64/2;     // bf16 new_node
  float* w2t      = p; p += 3*4096;
  float* et1t     = p; p += 128*64;
  float* nt1t     = p; p += 64*32;
  float* w1t      = p; p += 3*NC*DIM;
  bf16x8* wfrag   = (bf16x8*)p; p += 9*16*64*4;             // 144KB fragment tables
  __hip_bfloat16* tabb = (__hip_bfloat16*)p; p += (size_t)3*TABP*DIM/2;
  unsigned int* csr      = (unsigned int*)p; p += E;
  unsigned int* flagbits = (unsigned int*)p; p += FW;
  unsigned int* gbcnt    = (unsigned int*)p; p += NB;
  unsigned int* bscan    = (unsigned int*)p; p += NB+1;
  unsigned int* gcursor  = (unsigned int*)p; p += NB;
  int* offs              = (int*)p; p += N+1;

  // CSR build: two-level LDS counting sort
  hipMemsetAsync(gbcnt, 0, (size_t)NB*sizeof(int), stream);
  bhist_kernel<<<nbE, 256, 0, stream>>>(dst, gbcnt, flagbits, E, NB, FW);
  sel_mark_kernel<<<(K+255)/256, 256, 0, stream>>>(sel, flagbits, K);
  prep_transpose_kernel<<<48, 256, 0, stream>>>(cf_w2, et1_w, nt1_w, cf_w1,
                                                w2t, et1t, nt1t, w1t);
  wprep2_kernel<<<18, 256, 0, stream>>>(conv_w1, nl2_w, nl3_w, wfrag);
  bscan_kernel<<<1, NBMAX, 0, stream>>>(gbcnt, bscan, gcursor, offs, NB, N, E);
  passA_kernel<<<nbE, 256, 0, stream>>>(dst, src, dist, flagbits, gcursor, bbuf, E, NB);
  passB_kernel<<<NB, 256, 0, stream>>>(bbuf, bscan, offs, csr, N);
  // filter tables (3 layers, wave=row, nearest-neighbor bf16)
  table_kernel<<<(3*TABP+3)/4, 256, 0, stream>>>(edge_mask, w1t, cf_b1, w2t, cf_b2, tabb);

  int nbP  = (N+63)/64;    // node-panel blocks (64 nodes/block, 4 waves)
  int nb_agg = (N+3)/4;    // 4 waves/block x 1 node/wave
  node_init8_kernel<<<nbP, 256, 0, stream>>>(emb, node_type, wfrag, node, nnb, N);
  for (int l=0;l<3;l++){
    agg_kernel<<<nb_agg, 256, 0, stream>>>(csr, offs,
        (const unsigned short*)(tabb + (size_t)l*TABP*DIM), nnb, agg, N);
    if (l < 2)
      node_update8_kernel<true><<<nbP, 256, 0, stream>>>(node, agg,
          wfrag + (3+l)*16*64, nl2_b + l*64,
          wfrag + (6+l)*16*64, nl3_b + l*64,
          wfrag + (1+l)*16*64, nnb, N);
    else
      node_update8_kernel<false><<<nbP, 256, 0, stream>>>(node, agg,
          wfrag + (3+l)*16*64, nl2_b + l*64,
          wfrag + (6+l)*16*64, nl3_b + l*64,
          nullptr, nullptr, N);
  }

  node_head_kernel<<<(NSEL+3)/4, 256, 0, stream>>>(node, node_index,
      nt1t, nt1_b, nt2_w, nt2_b, (float*)d_out, NSEL);
  edge_head_kernel<<<(ESEL+15)/16, 256, 0, stream>>>(node, source_index, target_index,
      et1t, et1_b, et2_w, et2_b, (float*)d_out + (size_t)NSEL*3, ESEL);
}

// Round 16
// 307.715 us; speedup vs baseline: 7.1032x; 1.0703x over previous
//
#include <hip/hip_runtime.h>
#include <hip/hip_bf16.h>

#define DIM 64
#define NC 50
#define TABN 4096
#define TABP (TABN + 2)   // rows 0..4096 = h at p*5/4096, row 4097 = mask row
#define EPB 4096          // edges per block in CSR build
#define NBMAX 512         // max buckets (N <= 65536)

typedef short bf16x8 __attribute__((ext_vector_type(8)));
typedef float f32x4  __attribute__((ext_vector_type(4)));
#define MFMA(a,b,c) __builtin_amdgcn_mfma_f32_16x16x32_bf16(a,b,c,0,0,0)

__device__ __forceinline__ float sp_f(float x){
  // torch Softplus(beta=0.5, threshold=14): 2*log(1+exp(0.5x)), linear when 0.5*x>14
  float e = __expf(0.5f*x);
  float s = 2.0f*__logf(1.0f+e);
  return x > 28.0f ? x : s;
}

__device__ __forceinline__ float rdl(float v, int l){
  return __int_as_float(__builtin_amdgcn_readlane(__float_as_int(v), l));
}

__device__ __forceinline__ unsigned short b16(float x){
  __hip_bfloat16 h = __float2bfloat16(x);
  return __builtin_bit_cast(unsigned short, h);
}

// split x into hi + lo bf16 (lo = bf16(x - float(hi))) -> ~fp32 via 3-term MFMA
__device__ __forceinline__ void wsplit(float x, unsigned short& h, unsigned short& l){
  h = b16(x);
  float hf = __uint_as_float(((unsigned int)h) << 16);
  l = b16(x - hf);
}

// ---------------- CSR build: two-level LDS counting sort ----------------

__global__ __launch_bounds__(256) void bhist_kernel(const int* __restrict__ dst,
                                                    unsigned int* __restrict__ gbcnt,
                                                    unsigned int* __restrict__ flagbits,
                                                    int E, int NB, int FW){
  __shared__ unsigned int cnt[NBMAX];
  int tid = threadIdx.x;
  for (int b=tid; b<NB; b+=256) cnt[b] = 0;
  __syncthreads();
  int e0 = blockIdx.x*EPB, eend = min(e0+EPB, E);
  for (int e=e0+tid; e<eend; e+=256) atomicAdd(&cnt[dst[e]>>7], 1u);
  for (int w = blockIdx.x*256+tid; w < FW; w += gridDim.x*256) flagbits[w] = 0;
  __syncthreads();
  for (int b=tid; b<NB; b+=256) if (cnt[b]) atomicAdd(&gbcnt[b], cnt[b]);
}

__global__ void sel_mark_kernel(const int* __restrict__ sel,
                                unsigned int* __restrict__ flagbits, int K){
  int id = blockIdx.x*256 + threadIdx.x;
  if (id < K){ int e = sel[id]; atomicOr(&flagbits[e>>5], 1u << (e&31)); }
}

__global__ __launch_bounds__(NBMAX) void bscan_kernel(const unsigned int* __restrict__ gbcnt,
                                                      unsigned int* __restrict__ bscan,
                                                      unsigned int* __restrict__ gcursor,
                                                      int* __restrict__ offs,
                                                      int NB, int N, int E){
  __shared__ unsigned int s[NBMAX];
  int tid = threadIdx.x;
  unsigned int v = (tid < NB) ? gbcnt[tid] : 0;
  s[tid] = v;
  __syncthreads();
  for (int off=1; off<NBMAX; off<<=1){
    unsigned int u = (tid >= off) ? s[tid-off] : 0;
    __syncthreads();
    s[tid] += u;
    __syncthreads();
  }
  unsigned int excl = s[tid] - v;
  if (tid < NB){ bscan[tid] = excl; gcursor[tid] = excl; }
  if (tid == NB-1) bscan[NB] = excl + v;
  if (tid == 0) offs[N] = E;
}

// bucket-scatter with LOCAL bucket-major reorder -> coalesced global writes.
// Phase 1: histogram (dst cached in regs). Phase 2: block scan (2 buckets/thread)
// fused with gcursor chunk reservation; cnt[] becomes the local cursor.
// Phase 3: scatter entries into LDS at bucket-major positions.
// Phase 4: stream LDS sequentially; entry i -> bbuf[gdst[bucket(i)] + i]
// (consecutive i within a bucket = consecutive addresses -> sector-merged).
__global__ __launch_bounds__(256) void passA_kernel(const int* __restrict__ dst,
                                                    const int* __restrict__ src,
                                                    const float* __restrict__ dist,
                                                    const unsigned int* __restrict__ flagbits,
                                                    unsigned int* __restrict__ gcursor,
                                                    unsigned long long* __restrict__ bbuf,
                                                    int E, int NB){
  __shared__ unsigned int cnt[NBMAX];     // counts -> local cursor
  __shared__ unsigned int gdst[NBMAX];    // chunkbase[b] - lexcl[b]
  __shared__ unsigned int wpart[4];
  __shared__ unsigned long long lbuf[EPB];
  int tid = threadIdx.x, lane = tid & 63, wv = tid >> 6;
  for (int b=tid; b<NB; b+=256) cnt[b] = 0;
  __syncthreads();
  int e0 = blockIdx.x*EPB;
  int m = E - e0; if (m > EPB) m = EPB;
  int dreg[16];
  #pragma unroll
  for (int i=0;i<16;i++){
    int li = tid + 256*i;
    dreg[i] = (li < m) ? dst[e0 + li] : -1;
    if (dreg[i] >= 0) atomicAdd(&cnt[dreg[i]>>7], 1u);
  }
  __syncthreads();
  // block exclusive scan over NB buckets (2 per thread) + chunk reservation
  int t2 = tid*2;
  unsigned c0 = (t2 < NB) ? cnt[t2] : 0;
  unsigned c1 = (t2+1 < NB) ? cnt[t2+1] : 0;
  unsigned pv = c0 + c1, x = pv;
  #pragma unroll
  for (int off=1; off<64; off<<=1){ unsigned u = __shfl_up(x, off); if (lane >= off) x += u; }
  if (lane == 63) wpart[wv] = x;
  __syncthreads();
  unsigned wb = 0;
  #pragma unroll
  for (int q=0;q<4;q++) wb += (q < wv) ? wpart[q] : 0;
  unsigned ex0 = wb + x - pv;
  unsigned ex1 = ex0 + c0;
  if (t2 < NB){
    unsigned gb = c0 ? atomicAdd(&gcursor[t2], c0) : 0u;
    gdst[t2] = gb - ex0;
    cnt[t2]  = ex0;                      // local cursor (owner thread only)
  }
  if (t2+1 < NB){
    unsigned gb = c1 ? atomicAdd(&gcursor[t2+1], c1) : 0u;
    gdst[t2+1] = gb - ex1;
    cnt[t2+1]  = ex1;
  }
  __syncthreads();
  // local scatter (bucket-major); stash full dst in hi for phase 4
  #pragma unroll
  for (int i=0;i<16;i++){
    if (dreg[i] < 0) continue;
    int li = tid + 256*i;
    int e = e0 + li;
    int d = dreg[i];
    unsigned pos = atomicAdd(&cnt[d>>7], 1u);
    float tq = fminf(dist[e], 5.f) * ((float)TABN/5.0f);
    int idx = (int)(tq + 0.5f); if (idx > TABN) idx = TABN;   // nearest grid point
    if ((flagbits[e>>5] >> (e&31)) & 1u) idx = TABN+1;        // mask row
    unsigned lo = ((unsigned int)src[e] << 16) | (unsigned int)idx;
    lbuf[pos] = ((unsigned long long)(unsigned int)d << 32) | lo;
  }
  __syncthreads();
  // coalesced write-out
  for (int i=tid; i<m; i+=256){
    unsigned long long v = lbuf[i];
    unsigned d = (unsigned int)(v >> 32);
    unsigned addr = gdst[d>>7] + (unsigned int)i;   // = chunkbase + (i - lexcl)
    bbuf[addr] = (v & 0xFFFFFFFFull) | ((unsigned long long)(d & 127u) << 32);
  }
}

__global__ __launch_bounds__(256) void passB_kernel(const unsigned long long* __restrict__ bbuf,
                                                    const unsigned int* __restrict__ bscan,
                                                    int* __restrict__ offs,
                                                    unsigned int* __restrict__ csr,
                                                    int N){
  __shared__ unsigned int cnt[128];
  __shared__ unsigned int excl[128];
  int b = blockIdx.x, tid = threadIdx.x;
  unsigned int s0 = bscan[b];
  int m = (int)(bscan[b+1] - s0);
  if (tid < 128) cnt[tid] = 0;
  __syncthreads();
  for (int i=tid; i<m; i+=256)
    atomicAdd(&cnt[(unsigned int)(bbuf[s0+i] >> 32)], 1u);
  __syncthreads();
  if (tid < 128) excl[tid] = cnt[tid];
  __syncthreads();
  for (int off=1; off<128; off<<=1){
    unsigned int v = (tid < 128 && tid >= off) ? excl[tid-off] : 0;
    __syncthreads();
    if (tid < 128) excl[tid] += v;
    __syncthreads();
  }
  int node0 = b << 7;
  if (tid < 128){
    unsigned int ex = excl[tid] - cnt[tid];    // exclusive
    int n = node0 + tid;
    if (n < N) offs[n] = (int)(s0 + ex);
    excl[tid] = ex;
    cnt[tid] = 0;                              // reuse as cursor
  }
  __syncthreads();
  for (int i=tid; i<m; i+=256){
    unsigned long long v = bbuf[s0+i];
    unsigned int hi = (unsigned int)(v >> 32);
    unsigned int loc = atomicAdd(&cnt[hi], 1u);
    csr[s0 + excl[hi] + loc] = (unsigned int)v;
  }
}

// ---------------- prep: weight transposes (table + heads only) ----------------

__global__ void prep_transpose_kernel(const float* __restrict__ cf_w2,
                                      const float* __restrict__ et1_w,
                                      const float* __restrict__ nt1_w,
                                      const float* __restrict__ cf_w1,
                                      float* __restrict__ w2t,
                                      float* __restrict__ et1t,
                                      float* __restrict__ nt1t,
                                      float* __restrict__ w1t){
  int id = blockIdx.x*256 + threadIdx.x;
  if (id < 3*4096){
    int i = id >> 12, r = id & 4095;
    int k = r >> 6, j = r & 63;
    w2t[id]  = cf_w2[i*4096 + j*64 + k];
  }
  if (id < 128*64){
    int k = id >> 6, j = id & 63;
    et1t[id] = et1_w[j*128 + k];   // et1_w is [64][128]
  }
  if (id < 64*32){
    int k = id >> 5, j = id & 31;
    nt1t[id] = nt1_w[j*64 + k];    // nt1_w is [32][64]
  }
  if (id < 3*NC*DIM){              // cf_w1 [3][64][50] -> w1t [3][50][64]
    int l = id / (NC*DIM);
    int r = id - l*(NC*DIM);
    int m = r >> 6, k = r & 63;
    w1t[id] = cf_w1[l*DIM*NC + k*NC + m];
  }
}

// ---------------- weight fragment tables (one-time; L2-hot, 144KB) ----------------

__global__ void wprep2_kernel(const float* __restrict__ cw1,
                              const float* __restrict__ nl2,
                              const float* __restrict__ nl3,
                              bf16x8* __restrict__ wfrag){
  int id = blockIdx.x*256 + threadIdx.x;     // 9*8*64 = 4608 units
  if (id >= 9*8*64) return;
  int lane = id & 63;
  int f8 = (id >> 6) & 7;                    // nt*2 + ks
  int m  = id >> 9;
  int nt = f8 >> 1, ks = f8 & 1;
  const float* W = (m < 3) ? (cw1 + m*4096)
                 : (m < 6) ? (nl2 + (m-3)*4096)
                           : (nl3 + (m-6)*4096);
  int j  = nt*16 + (lane & 15);
  int k0 = ks*32 + (lane >> 4)*8;
  bf16x8 vh, vl;
  #pragma unroll
  for (int u=0;u<8;u++){
    unsigned short h,l;
    wsplit(W[j*64 + k0 + u], h, l);
    vh[u] = (short)h; vl[u] = (short)l;
  }
  int fb = m*16 + nt*4 + ks*2;
  wfrag[(fb+0)*64 + lane] = vh;
  wfrag[(fb+1)*64 + lane] = vl;
}

// ---------------- filter table (bf16, nearest), wave = row, lane = feature ----------

__global__ __launch_bounds__(256) void table_kernel(const float* __restrict__ edge_mask,
                                                    const float* __restrict__ w1t,   // [3][50][64]
                                                    const float* __restrict__ cf_b1,
                                                    const float* __restrict__ w2t,   // [3][64][64]
                                                    const float* __restrict__ cf_b2,
                                                    __hip_bfloat16* __restrict__ tabb){
  int row = blockIdx.x*4 + (threadIdx.x >> 6);
  if (row >= 3*TABP) return;
  int l = row / TABP, p = row - l*TABP;
  int lane = threadIdx.x & 63;
  float rbfv = 0.f;
  if (lane < NC){
    if (p == TABN+1) rbfv = edge_mask[lane];
    else {
      float d = (float)p * (5.0f/(float)TABN);
      float c = (lane == NC-1) ? 5.0f : (float)((double)lane * (5.0/49.0));
      float df = d - c;
      rbfv = __expf((float)(-1.0/(5.0/49.0)) * df * df);
    }
  }
  const float* W1 = w1t + l*NC*DIM;
  float t = cf_b1[l*DIM + lane];
  #pragma unroll 10
  for (int m=0;m<NC;m++)
    t = fmaf(rdl(rbfv, m), W1[m*64 + lane], t);
  float su = sp_f(t);
  const float* W2 = w2t + l*DIM*DIM;
  float h = cf_b2[l*DIM + lane];
  #pragma unroll 16
  for (int k=0;k<DIM;k++)
    h = fmaf(rdl(su, k), W2[k*64 + lane], h);
  tabb[((size_t)l*TABP + p)*DIM + lane] = __float2bfloat16(h);
}

// ---------------- node-side v8: MFMA, weights from global fragment tables --------

__device__ __forceinline__ bf16x8 ldfrag(const char* base, int rowbase, int ks, int lane){
  int r = lane & 15;
  int off = (ks<<6) + ((lane>>4)<<4);
  return *(const bf16x8*)(base + (rowbase + r)*128 + (off ^ ((r & 7)<<4)));
}

__device__ __forceinline__ void stx(char* XH, char* XLo, int row, int col, float v){
  unsigned short h,l;
  wsplit(v, h, l);
  int off = row*128 + ((col*2) ^ ((row&7)<<4));
  *(unsigned short*)(XH + off) = h;
  *(unsigned short*)(XLo + off) = l;
}

#define MM6G(WF, NT, ACC) \
  { ACC = MFMA(ah0, (WF)[((NT)*4+0)*64 + lane], ACC); \
    ACC = MFMA(ah1, (WF)[((NT)*4+2)*64 + lane], ACC); \
    ACC = MFMA(ah0, (WF)[((NT)*4+1)*64 + lane], ACC); \
    ACC = MFMA(ah1, (WF)[((NT)*4+3)*64 + lane], ACC); \
    ACC = MFMA(al0, (WF)[((NT)*4+0)*64 + lane], ACC); \
    ACC = MFMA(al1, (WF)[((NT)*4+2)*64 + lane], ACC); }

#define LDA(XH_, XLo_) \
  bf16x8 ah0 = ldfrag(XH_, mb, 0, lane), ah1 = ldfrag(XH_, mb, 1, lane); \
  bf16x8 al0 = ldfrag(XLo_, mb, 0, lane), al1 = ldfrag(XLo_, mb, 1, lane);

// node = emb[node_type]; nnb = bf16(node @ conv_w1[0]^T)
__global__ __launch_bounds__(256) void node_init8_kernel(const float* __restrict__ emb,
                                                         const int* __restrict__ node_type,
                                                         const bf16x8* __restrict__ wf0,
                                                         float* __restrict__ node,
                                                         unsigned short* __restrict__ nout, int N){
  __shared__ __align__(16) char XP[16384];
  char *XH = XP, *XLo = XP + 8192;
  int tid = threadIdx.x, lane = tid & 63, wv = tid >> 6;
  int nb = blockIdx.x*64, mb = wv*16;
  #pragma unroll
  for (int t=0;t<16;t++){
    int row = mb + t, n = nb + row;
    int ty = (n < N) ? node_type[n] : 0;
    float v = emb[(long)ty*64 + lane];
    if (n < N) node[(long)n*64 + lane] = v;
    stx(XH, XLo, row, lane, v);
  }
  __syncthreads();
  LDA(XH, XLo)
  #pragma unroll
  for (int nt=0; nt<4; nt++){
    f32x4 acc = {0.f,0.f,0.f,0.f};
    MM6G(wf0, nt, acc)
    int col = nt*16 + (lane&15);
    #pragma unroll
    for (int v=0; v<4; v++){
      int n = nb + mb + ((lane>>4)<<2) + v;
      if (n < N) nout[(long)n*64 + col] = b16(acc[v]);
    }
  }
}

// node += sp(agg@nl2^T+b2)@nl3^T+b3; optionally nnb = bf16(node_new @ cw1_next^T)
template<bool PRODUCE_NN>
__global__ __launch_bounds__(256) void node_update8_kernel(float* __restrict__ node,
                                                           const float* __restrict__ agg,
                                                           const bf16x8* __restrict__ wfA, // nl2 frags
                                                           const float* __restrict__ nl2_b,
                                                           const bf16x8* __restrict__ wfB, // nl3 frags
                                                           const float* __restrict__ nl3_b,
                                                           const bf16x8* __restrict__ wfC, // cw1_next
                                                           unsigned short* __restrict__ nout, int N){
  __shared__ __align__(16) char XP[16384];
  char *XH = XP, *XLo = XP + 8192;
  int tid = threadIdx.x, lane = tid & 63, wv = tid >> 6;
  int nb = blockIdx.x*64, mb = wv*16;
  // stage agg rows (wave-local)
  #pragma unroll
  for (int t=0;t<16;t++){
    int row = mb + t, n = nb + row;
    float v = (n < N) ? agg[(long)n*64 + lane] : 0.f;
    stx(XH, XLo, row, lane, v);
  }
  __syncthreads();
  // matmul1: S = sp(X @ nl2^T + b2) -> back into X panels (own rows)
  {
    LDA(XH, XLo)
    #pragma unroll
    for (int nt=0; nt<4; nt++){
      float bb = nl2_b[nt*16 + (lane&15)];
      f32x4 acc = {bb,bb,bb,bb};
      MM6G(wfA, nt, acc)
      int col = nt*16 + (lane&15);
      #pragma unroll
      for (int v=0; v<4; v++){
        int row = mb + ((lane>>4)<<2) + v;
        stx(XH, XLo, row, col, sp_f(acc[v]));
      }
    }
  }
  // matmul2: node_new = node + S @ nl3^T + b3 -> node (f32) and X panels
  {
    LDA(XH, XLo)
    #pragma unroll
    for (int nt=0; nt<4; nt++){
      float bb = nl3_b[nt*16 + (lane&15)];
      f32x4 acc = {bb,bb,bb,bb};
      MM6G(wfB, nt, acc)
      int col = nt*16 + (lane&15);
      #pragma unroll
      for (int v=0; v<4; v++){
        int row = mb + ((lane>>4)<<2) + v;
        int n = nb + row;
        float nv = 0.f;
        if (n < N){
          long g = (long)n*64 + col;
          nv = node[g] + acc[v];
          node[g] = nv;
        }
        stx(XH, XLo, row, col, nv);
      }
    }
  }
  if (PRODUCE_NN){
    LDA(XH, XLo)
    #pragma unroll
    for (int nt=0; nt<4; nt++){
      f32x4 acc = {0.f,0.f,0.f,0.f};
      MM6G(wfC, nt, acc)
      int col = nt*16 + (lane&15);
      #pragma unroll
      for (int v=0; v<4; v++){
        int n = nb + mb + ((lane>>4)<<2) + v;
        if (n < N) nout[(long)n*64 + col] = b16(acc[v]);
      }
    }
  }
}

// gather-aggregate: wave = 1 dst node, lane = feature; 4B csr, bf16 table + new_node
__global__ __launch_bounds__(256) void agg_kernel(const unsigned int* __restrict__ csr,
                                                  const int* __restrict__ offs,
                                                  const unsigned short* __restrict__ tab,  // [TABP][64] bf16
                                                  const unsigned short* __restrict__ nnb,  // bf16 bits
                                                  float* __restrict__ agg, int N){
  int n = blockIdx.x*4 + (threadIdx.x >> 6);
  int lane = threadIdx.x & 63;
  if (n >= N) return;
  int beg = offs[n], end = offs[n+1];
  float acc = 0.f;
  for (int c = beg; c < end; c += 64){
    int m = end - c; if (m > 64) m = 64;
    unsigned int pkv = csr[c + (lane < m ? lane : 0)];   // coalesced edge-list load
    int q = 0;
    for (; q + 8 <= m; q += 8){
      #pragma unroll
      for (int u=0; u<8; u++){
        unsigned int p = (unsigned int)__builtin_amdgcn_readlane((int)pkv, q+u); // SGPR
        int idx = p & 0xFFFF, s = p >> 16;
        float a  = __uint_as_float(((unsigned int)tab[idx*64 + lane]) << 16);
        float nn = __uint_as_float(((unsigned int)nnb[(long)s*64 + lane]) << 16);
        acc = fmaf(nn, a, acc);
      }
    }
    for (; q < m; q++){
      unsigned int p = (unsigned int)__builtin_amdgcn_readlane((int)pkv, q);
      int idx = p & 0xFFFF, s = p >> 16;
      float a  = __uint_as_float(((unsigned int)tab[idx*64 + lane]) << 16);
      float nn = __uint_as_float(((unsigned int)nnb[(long)s*64 + lane]) << 16);
      acc = fmaf(nn, a, acc);
    }
  }
  agg[(long)n*64 + lane] = acc;
}

// ---------------- heads ----------------

__global__ __launch_bounds__(256) void node_head_kernel(const float* __restrict__ node,
                                                        const int* __restrict__ nidx,
                                                        const float* __restrict__ nt1t,  // [64][32]
                                                        const float* __restrict__ nt1_b,
                                                        const float* __restrict__ nt2_w, // [3][32]
                                                        const float* __restrict__ nt2_b,
                                                        float* __restrict__ out, int NSEL){
  int r = __builtin_amdgcn_readfirstlane(blockIdx.x*4 + (threadIdx.x>>6));
  int lane = threadIdx.x & 63;
  if (r >= NSEL) return;
  long n = nidx[r];
  const float* x = node + n*64;                    // uniform -> s_loads
  float u = 0.f;
  if (lane < 32){
    u = nt1_b[lane];
    #pragma unroll
    for (int k=0;k<DIM;k++) u += x[k]*nt1t[k*32 + lane];
  }
  #pragma unroll
  for (int q=0;q<3;q++){
    float v = (lane < 32) ? u*nt2_w[q*32 + lane] : 0.f;
    #pragma unroll
    for (int o=32;o>=1;o>>=1) v += __shfl_xor(v, o);
    if (lane == 0) out[(long)r*3 + q] = nt2_b[q] + v;
  }
}

__global__ __launch_bounds__(256) void edge_head_kernel(const float* __restrict__ node,
                                                        const int* __restrict__ sidx,
                                                        const int* __restrict__ tidx,
                                                        const float* __restrict__ et1t, // [128][64]
                                                        const float* __restrict__ et1_b,
                                                        const float* __restrict__ et2_w,// [5][64]
                                                        const float* __restrict__ et2_b,
                                                        float* __restrict__ out, int ESEL){
  int wid = threadIdx.x >> 6, lane = threadIdx.x & 63;
  int r0 = (blockIdx.x*4 + wid)*4;
  if (r0 >= ESEL) return;
  float xs[4], xt[4], acc[4];
  #pragma unroll
  for (int i=0;i<4;i++){
    int r = r0+i < ESEL ? r0+i : ESEL-1;
    long s = sidx[r], t = tidx[r];
    xs[i] = node[s*64 + lane];
    xt[i] = node[t*64 + lane];
    acc[i] = et1_b[lane];
  }
  #pragma unroll 16
  for (int k=0;k<DIM;k++){
    float w1 = et1t[k*64 + lane];
    float w2 = et1t[(64+k)*64 + lane];
    #pragma unroll
    for (int i=0;i<4;i++){
      acc[i] = fmaf(rdl(xs[i], k), w1, acc[i]);
      acc[i] = fmaf(rdl(xt[i], k), w2, acc[i]);
    }
  }
  #pragma unroll
  for (int i=0;i<4;i++){
    if (r0+i >= ESEL) break;
    #pragma unroll
    for (int q=0;q<5;q++){
      float v = acc[i]*et2_w[q*64 + lane];
      #pragma unroll
      for (int o=32;o>=1;o>>=1) v += __shfl_xor(v, o);
      if (lane == 0) out[(long)(r0+i)*5 + q] = et2_b[q] + v;
    }
  }
}

// ---------------- launch ----------------

extern "C" void kernel_launch(void* const* d_in, const int* in_sizes, int n_in,
                              void* d_out, int out_size, void* d_ws, size_t ws_size,
                              hipStream_t stream){
  const float* emb      = (const float*)d_in[0];
  const float* dist     = (const float*)d_in[1];
  const float* edge_mask= (const float*)d_in[2];
  const float* conv_w1  = (const float*)d_in[3];
  const float* cf_w1    = (const float*)d_in[4];
  const float* cf_b1    = (const float*)d_in[5];
  const float* cf_w2    = (const float*)d_in[6];
  const float* cf_b2    = (const float*)d_in[7];
  const float* nl2_w    = (const float*)d_in[8];
  const float* nl2_b    = (const float*)d_in[9];
  const float* nl3_w    = (const float*)d_in[10];
  const float* nl3_b    = (const float*)d_in[11];
  const float* nt1_w    = (const float*)d_in[12];
  const float* nt1_b    = (const float*)d_in[13];
  const float* nt2_w    = (const float*)d_in[14];
  const float* nt2_b    = (const float*)d_in[15];
  const float* et1_w    = (const float*)d_in[16];
  const float* et1_b    = (const float*)d_in[17];
  const float* et2_w    = (const float*)d_in[18];
  const float* et2_b    = (const float*)d_in[19];
  const int* node_type  = (const int*)d_in[20];
  const int* src        = (const int*)d_in[21];
  const int* dst        = (const int*)d_in[22];
  const int* sel        = (const int*)d_in[23];
  const int* node_index = (const int*)d_in[24];
  const int* source_index = (const int*)d_in[25];
  const int* target_index = (const int*)d_in[26];

  int E    = in_sizes[1];
  int N    = in_sizes[20];
  int K    = in_sizes[23];
  int NSEL = in_sizes[24];
  int ESEL = in_sizes[25];

  int NB  = (N + 127) >> 7;           // buckets of 128 nodes
  int FW  = (E + 31) >> 5;            // flag words
  int nbE = (E + EPB - 1) / EPB;      // CSR-build blocks

  size_t N64 = (size_t)N*64;
  // bbuf (E u64) first for 8B alignment; agg aliases it (lifetimes disjoint)
  unsigned long long* bbuf = (unsigned long long*)d_ws;
  float* agg = (float*)d_ws;
  size_t aggsz = ((size_t)2*E > N64) ? (size_t)2*E : N64;   // float units
  float* p = (float*)d_ws + aggsz;
  float* node     = p; p += N64;
  unsigned short* nnb = (unsigned short*)p; p += N64/2;     // bf16 new_node
  float* w2t      = p; p += 3*4096;
  float* et1t     = p; p += 128*64;
  float* nt1t     = p; p += 64*32;
  float* w1t      = p; p += 3*NC*DIM;
  bf16x8* wfrag   = (bf16x8*)p; p += 9*16*64*4;             // 144KB fragment tables
  __hip_bfloat16* tabb = (__hip_bfloat16*)p; p += (size_t)3*TABP*DIM/2;
  unsigned int* csr      = (unsigned int*)p; p += E;
  unsigned int* flagbits = (unsigned int*)p; p += FW;
  unsigned int* gbcnt    = (unsigned int*)p; p += NB;
  unsigned int* bscan    = (unsigned int*)p; p += NB+1;
  unsigned int* gcursor  = (unsigned int*)p; p += NB;
  int* offs              = (int*)p; p += N+1;

  // CSR build: two-level LDS counting sort
  hipMemsetAsync(gbcnt, 0, (size_t)NB*sizeof(int), stream);
  bhist_kernel<<<nbE, 256, 0, stream>>>(dst, gbcnt, flagbits, E, NB, FW);
  sel_mark_kernel<<<(K+255)/256, 256, 0, stream>>>(sel, flagbits, K);
  prep_transpose_kernel<<<48, 256, 0, stream>>>(cf_w2, et1_w, nt1_w, cf_w1,
                                                w2t, et1t, nt1t, w1t);
  wprep2_kernel<<<18, 256, 0, stream>>>(conv_w1, nl2_w, nl3_w, wfrag);
  bscan_kernel<<<1, NBMAX, 0, stream>>>(gbcnt, bscan, gcursor, offs, NB, N, E);
  passA_kernel<<<nbE, 256, 0, stream>>>(dst, src, dist, flagbits, gcursor, bbuf, E, NB);
  passB_kernel<<<NB, 256, 0, stream>>>(bbuf, bscan, offs, csr, N);
  // filter tables (3 layers, wave=row, nearest-neighbor bf16)
  table_kernel<<<(3*TABP+3)/4, 256, 0, stream>>>(edge_mask, w1t, cf_b1, w2t, cf_b2, tabb);

  int nbP  = (N+63)/64;    // node-panel blocks (64 nodes/block, 4 waves)
  int nb_agg = (N+3)/4;    // 4 waves/block x 1 node/wave
  node_init8_kernel<<<nbP, 256, 0, stream>>>(emb, node_type, wfrag, node, nnb, N);
  for (int l=0;l<3;l++){
    agg_kernel<<<nb_agg, 256, 0, stream>>>(csr, offs,
        (const unsigned short*)(tabb + (size_t)l*TABP*DIM), nnb, agg, N);
    if (l < 2)
      node_update8_kernel<true><<<nbP, 256, 0, stream>>>(node, agg,
          wfrag + (3+l)*16*64, nl2_b + l*64,
          wfrag + (6+l)*16*64, nl3_b + l*64,
          wfrag + (1+l)*16*64, nnb, N);
    else
      node_update8_kernel<false><<<nbP, 256, 0, stream>>>(node, agg,
          wfrag + (3+l)*16*64, nl2_b + l*64,
          wfrag + (6+l)*16*64, nl3_b + l*64,
          nullptr, nullptr, N);
  }

  node_head_kernel<<<(NSEL+3)/4, 256, 0, stream>>>(node, node_index,
      nt1t, nt1_b, nt2_w, nt2_b, (float*)d_out, NSEL);
  edge_head_kernel<<<(ESEL+15)/16, 256, 0, stream>>>(node, source_index, target_index,
      et1t, et1_b, et2_w, et2_b, (float*)d_out + (size_t)NSEL*3, ESEL);
}

// Round 17
// 298.060 us; speedup vs baseline: 7.3333x; 1.0324x over previous
//
#include <hip/hip_runtime.h>
#include <hip/hip_bf16.h>

#define DIM 64
#define NC 50
#define TABN 4096
#define TABP (TABN + 2)   // rows 0..4096 = h at p*5/4096, row 4097 = mask row
#define EPB 4096          // edges per block in CSR build
#define NBMAX 512         // max buckets (N <= 65536)

typedef short bf16x8 __attribute__((ext_vector_type(8)));
typedef float f32x4  __attribute__((ext_vector_type(4)));
#define MFMA(a,b,c) __builtin_amdgcn_mfma_f32_16x16x32_bf16(a,b,c,0,0,0)

__device__ __forceinline__ float sp_f(float x){
  // torch Softplus(beta=0.5, threshold=14): 2*log(1+exp(0.5x)), linear when 0.5*x>14
  float e = __expf(0.5f*x);
  float s = 2.0f*__logf(1.0f+e);
  return x > 28.0f ? x : s;
}

__device__ __forceinline__ float rdl(float v, int l){
  return __int_as_float(__builtin_amdgcn_readlane(__float_as_int(v), l));
}

__device__ __forceinline__ unsigned short b16(float x){
  __hip_bfloat16 h = __float2bfloat16(x);
  return __builtin_bit_cast(unsigned short, h);
}

// split x into hi + lo bf16 (lo = bf16(x - float(hi))) -> ~fp32 via 3-term MFMA
__device__ __forceinline__ void wsplit(float x, unsigned short& h, unsigned short& l){
  h = b16(x);
  float hf = __uint_as_float(((unsigned int)h) << 16);
  l = b16(x - hf);
}

// ---------------- CSR build: two-level LDS counting sort ----------------

__global__ __launch_bounds__(256) void bhist_kernel(const int* __restrict__ dst,
                                                    unsigned int* __restrict__ gbcnt,
                                                    unsigned int* __restrict__ flagbits,
                                                    int E, int NB, int FW){
  __shared__ unsigned int cnt[NBMAX];
  int tid = threadIdx.x;
  for (int b=tid; b<NB; b+=256) cnt[b] = 0;
  __syncthreads();
  int e0 = blockIdx.x*EPB, eend = min(e0+EPB, E);
  for (int e=e0+tid; e<eend; e+=256) atomicAdd(&cnt[dst[e]>>7], 1u);
  for (int w = blockIdx.x*256+tid; w < FW; w += gridDim.x*256) flagbits[w] = 0;
  __syncthreads();
  for (int b=tid; b<NB; b+=256) if (cnt[b]) atomicAdd(&gbcnt[b], cnt[b]);
}

__global__ void sel_mark_kernel(const int* __restrict__ sel,
                                unsigned int* __restrict__ flagbits, int K){
  int id = blockIdx.x*256 + threadIdx.x;
  if (id < K){ int e = sel[id]; atomicOr(&flagbits[e>>5], 1u << (e&31)); }
}

__global__ __launch_bounds__(NBMAX) void bscan_kernel(const unsigned int* __restrict__ gbcnt,
                                                      unsigned int* __restrict__ bscan,
                                                      unsigned int* __restrict__ gcursor,
                                                      int* __restrict__ offs,
                                                      int NB, int N, int E){
  __shared__ unsigned int s[NBMAX];
  int tid = threadIdx.x;
  unsigned int v = (tid < NB) ? gbcnt[tid] : 0;
  s[tid] = v;
  __syncthreads();
  for (int off=1; off<NBMAX; off<<=1){
    unsigned int u = (tid >= off) ? s[tid-off] : 0;
    __syncthreads();
    s[tid] += u;
    __syncthreads();
  }
  unsigned int excl = s[tid] - v;
  if (tid < NB){ bscan[tid] = excl; gcursor[tid] = excl; }
  if (tid == NB-1) bscan[NB] = excl + v;
  if (tid == 0) offs[N] = E;
}

// bucket-scatter with LOCAL bucket-major reorder -> coalesced global writes.
__global__ __launch_bounds__(256) void passA_kernel(const int* __restrict__ dst,
                                                    const int* __restrict__ src,
                                                    const float* __restrict__ dist,
                                                    const unsigned int* __restrict__ flagbits,
                                                    unsigned int* __restrict__ gcursor,
                                                    unsigned long long* __restrict__ bbuf,
                                                    int E, int NB){
  __shared__ unsigned int cnt[NBMAX];     // counts -> local cursor
  __shared__ unsigned int gdst[NBMAX];    // chunkbase[b] - lexcl[b]
  __shared__ unsigned int wpart[4];
  __shared__ unsigned long long lbuf[EPB];
  int tid = threadIdx.x, lane = tid & 63, wv = tid >> 6;
  for (int b=tid; b<NB; b+=256) cnt[b] = 0;
  __syncthreads();
  int e0 = blockIdx.x*EPB;
  int m = E - e0; if (m > EPB) m = EPB;
  int dreg[16];
  #pragma unroll
  for (int i=0;i<16;i++){
    int li = tid + 256*i;
    dreg[i] = (li < m) ? dst[e0 + li] : -1;
    if (dreg[i] >= 0) atomicAdd(&cnt[dreg[i]>>7], 1u);
  }
  __syncthreads();
  // block exclusive scan over NB buckets (2 per thread) + chunk reservation
  int t2 = tid*2;
  unsigned c0 = (t2 < NB) ? cnt[t2] : 0;
  unsigned c1 = (t2+1 < NB) ? cnt[t2+1] : 0;
  unsigned pv = c0 + c1, x = pv;
  #pragma unroll
  for (int off=1; off<64; off<<=1){ unsigned u = __shfl_up(x, off); if (lane >= off) x += u; }
  if (lane == 63) wpart[wv] = x;
  __syncthreads();
  unsigned wb = 0;
  #pragma unroll
  for (int q=0;q<4;q++) wb += (q < wv) ? wpart[q] : 0;
  unsigned ex0 = wb + x - pv;
  unsigned ex1 = ex0 + c0;
  if (t2 < NB){
    unsigned gb = c0 ? atomicAdd(&gcursor[t2], c0) : 0u;
    gdst[t2] = gb - ex0;
    cnt[t2]  = ex0;                      // local cursor
  }
  if (t2+1 < NB){
    unsigned gb = c1 ? atomicAdd(&gcursor[t2+1], c1) : 0u;
    gdst[t2+1] = gb - ex1;
    cnt[t2+1]  = ex1;
  }
  __syncthreads();
  // local scatter (bucket-major); stash full dst in hi for phase 4
  #pragma unroll
  for (int i=0;i<16;i++){
    if (dreg[i] < 0) continue;
    int li = tid + 256*i;
    int e = e0 + li;
    int d = dreg[i];
    unsigned pos = atomicAdd(&cnt[d>>7], 1u);
    float tq = fminf(dist[e], 5.f) * ((float)TABN/5.0f);
    int idx = (int)(tq + 0.5f); if (idx > TABN) idx = TABN;   // nearest grid point
    if ((flagbits[e>>5] >> (e&31)) & 1u) idx = TABN+1;        // mask row
    unsigned lo = ((unsigned int)src[e] << 16) | (unsigned int)idx;
    lbuf[pos] = ((unsigned long long)(unsigned int)d << 32) | lo;
  }
  __syncthreads();
  // coalesced write-out
  for (int i=tid; i<m; i+=256){
    unsigned long long v = lbuf[i];
    unsigned d = (unsigned int)(v >> 32);
    unsigned addr = gdst[d>>7] + (unsigned int)i;   // = chunkbase + (i - lexcl)
    bbuf[addr] = (v & 0xFFFFFFFFull) | ((unsigned long long)(d & 127u) << 32);
  }
}

__global__ __launch_bounds__(256) void passB_kernel(const unsigned long long* __restrict__ bbuf,
                                                    const unsigned int* __restrict__ bscan,
                                                    int* __restrict__ offs,
                                                    unsigned int* __restrict__ csr,
                                                    int N){
  __shared__ unsigned int cnt[128];
  __shared__ unsigned int excl[128];
  int b = blockIdx.x, tid = threadIdx.x;
  unsigned int s0 = bscan[b];
  int m = (int)(bscan[b+1] - s0);
  if (tid < 128) cnt[tid] = 0;
  __syncthreads();
  for (int i=tid; i<m; i+=256)
    atomicAdd(&cnt[(unsigned int)(bbuf[s0+i] >> 32)], 1u);
  __syncthreads();
  if (tid < 128) excl[tid] = cnt[tid];
  __syncthreads();
  for (int off=1; off<128; off<<=1){
    unsigned int v = (tid < 128 && tid >= off) ? excl[tid-off] : 0;
    __syncthreads();
    if (tid < 128) excl[tid] += v;
    __syncthreads();
  }
  int node0 = b << 7;
  if (tid < 128){
    unsigned int ex = excl[tid] - cnt[tid];    // exclusive
    int n = node0 + tid;
    if (n < N) offs[n] = (int)(s0 + ex);
    excl[tid] = ex;
    cnt[tid] = 0;                              // reuse as cursor
  }
  __syncthreads();
  for (int i=tid; i<m; i+=256){
    unsigned long long v = bbuf[s0+i];
    unsigned int hi = (unsigned int)(v >> 32);
    unsigned int loc = atomicAdd(&cnt[hi], 1u);
    csr[s0 + excl[hi] + loc] = (unsigned int)v;
  }
}

// ---------------- prep: weight transposes (table + heads only) ----------------

__global__ void prep_transpose_kernel(const float* __restrict__ cf_w2,
                                      const float* __restrict__ et1_w,
                                      const float* __restrict__ nt1_w,
                                      const float* __restrict__ cf_w1,
                                      float* __restrict__ w2t,
                                      float* __restrict__ et1t,
                                      float* __restrict__ nt1t,
                                      float* __restrict__ w1t){
  int id = blockIdx.x*256 + threadIdx.x;
  if (id < 3*4096){
    int i = id >> 12, r = id & 4095;
    int k = r >> 6, j = r & 63;
    w2t[id]  = cf_w2[i*4096 + j*64 + k];
  }
  if (id < 128*64){
    int k = id >> 6, j = id & 63;
    et1t[id] = et1_w[j*128 + k];   // et1_w is [64][128]
  }
  if (id < 64*32){
    int k = id >> 5, j = id & 31;
    nt1t[id] = nt1_w[j*64 + k];    // nt1_w is [32][64]
  }
  if (id < 3*NC*DIM){              // cf_w1 [3][64][50] -> w1t [3][50][64]
    int l = id / (NC*DIM);
    int r = id - l*(NC*DIM);
    int m = r >> 6, k = r & 63;
    w1t[id] = cf_w1[l*DIM*NC + k*NC + m];
  }
}

// ---------------- weight fragment tables (one-time; L2-hot, 144KB) ----------------

__global__ void wprep2_kernel(const float* __restrict__ cw1,
                              const float* __restrict__ nl2,
                              const float* __restrict__ nl3,
                              bf16x8* __restrict__ wfrag){
  int id = blockIdx.x*256 + threadIdx.x;     // 9*8*64 = 4608 units
  if (id >= 9*8*64) return;
  int lane = id & 63;
  int f8 = (id >> 6) & 7;                    // nt*2 + ks
  int m  = id >> 9;
  int nt = f8 >> 1, ks = f8 & 1;
  const float* W = (m < 3) ? (cw1 + m*4096)
                 : (m < 6) ? (nl2 + (m-3)*4096)
                           : (nl3 + (m-6)*4096);
  int j  = nt*16 + (lane & 15);
  int k0 = ks*32 + (lane >> 4)*8;
  bf16x8 vh, vl;
  #pragma unroll
  for (int u=0;u<8;u++){
    unsigned short h,l;
    wsplit(W[j*64 + k0 + u], h, l);
    vh[u] = (short)h; vl[u] = (short)l;
  }
  int fb = m*16 + nt*4 + ks*2;
  wfrag[(fb+0)*64 + lane] = vh;
  wfrag[(fb+1)*64 + lane] = vl;
}

// ---------------- filter table (bf16, nearest), wave = row, lane = feature ----------

__global__ __launch_bounds__(256) void table_kernel(const float* __restrict__ edge_mask,
                                                    const float* __restrict__ w1t,   // [3][50][64]
                                                    const float* __restrict__ cf_b1,
                                                    const float* __restrict__ w2t,   // [3][64][64]
                                                    const float* __restrict__ cf_b2,
                                                    __hip_bfloat16* __restrict__ tabb){
  int row = blockIdx.x*4 + (threadIdx.x >> 6);
  if (row >= 3*TABP) return;
  int l = row / TABP, p = row - l*TABP;
  int lane = threadIdx.x & 63;
  float rbfv = 0.f;
  if (lane < NC){
    if (p == TABN+1) rbfv = edge_mask[lane];
    else {
      float d = (float)p * (5.0f/(float)TABN);
      float c = (lane == NC-1) ? 5.0f : (float)((double)lane * (5.0/49.0));
      float df = d - c;
      rbfv = __expf((float)(-1.0/(5.0/49.0)) * df * df);
    }
  }
  const float* W1 = w1t + l*NC*DIM;
  float t = cf_b1[l*DIM + lane];
  #pragma unroll 10
  for (int m=0;m<NC;m++)
    t = fmaf(rdl(rbfv, m), W1[m*64 + lane], t);
  float su = sp_f(t);
  const float* W2 = w2t + l*DIM*DIM;
  float h = cf_b2[l*DIM + lane];
  #pragma unroll 16
  for (int k=0;k<DIM;k++)
    h = fmaf(rdl(su, k), W2[k*64 + lane], h);
  tabb[((size_t)l*TABP + p)*DIM + lane] = __float2bfloat16(h);
}

// ---------------- node-side v8: MFMA, weights from global fragment tables --------

__device__ __forceinline__ bf16x8 ldfrag(const char* base, int rowbase, int ks, int lane){
  int r = lane & 15;
  int off = (ks<<6) + ((lane>>4)<<4);
  return *(const bf16x8*)(base + (rowbase + r)*128 + (off ^ ((r & 7)<<4)));
}

__device__ __forceinline__ void stx(char* XH, char* XLo, int row, int col, float v){
  unsigned short h,l;
  wsplit(v, h, l);
  int off = row*128 + ((col*2) ^ ((row&7)<<4));
  *(unsigned short*)(XH + off) = h;
  *(unsigned short*)(XLo + off) = l;
}

#define MM6G(WF, NT, ACC) \
  { ACC = MFMA(ah0, (WF)[((NT)*4+0)*64 + lane], ACC); \
    ACC = MFMA(ah1, (WF)[((NT)*4+2)*64 + lane], ACC); \
    ACC = MFMA(ah0, (WF)[((NT)*4+1)*64 + lane], ACC); \
    ACC = MFMA(ah1, (WF)[((NT)*4+3)*64 + lane], ACC); \
    ACC = MFMA(al0, (WF)[((NT)*4+0)*64 + lane], ACC); \
    ACC = MFMA(al1, (WF)[((NT)*4+2)*64 + lane], ACC); }

#define LDA(XH_, XLo_) \
  bf16x8 ah0 = ldfrag(XH_, mb, 0, lane), ah1 = ldfrag(XH_, mb, 1, lane); \
  bf16x8 al0 = ldfrag(XLo_, mb, 0, lane), al1 = ldfrag(XLo_, mb, 1, lane);

// node = emb[node_type]; nnb = bf16(node @ conv_w1[0]^T)
__global__ __launch_bounds__(256) void node_init8_kernel(const float* __restrict__ emb,
                                                         const int* __restrict__ node_type,
                                                         const bf16x8* __restrict__ wf0,
                                                         float* __restrict__ node,
                                                         unsigned short* __restrict__ nout, int N){
  __shared__ __align__(16) char XP[16384];
  char *XH = XP, *XLo = XP + 8192;
  int tid = threadIdx.x, lane = tid & 63, wv = tid >> 6;
  int nb = blockIdx.x*64, mb = wv*16;
  #pragma unroll
  for (int t=0;t<16;t++){
    int row = mb + t, n = nb + row;
    int ty = (n < N) ? node_type[n] : 0;
    float v = emb[(long)ty*64 + lane];
    if (n < N) node[(long)n*64 + lane] = v;
    stx(XH, XLo, row, lane, v);
  }
  __syncthreads();
  LDA(XH, XLo)
  #pragma unroll
  for (int nt=0; nt<4; nt++){
    f32x4 acc = {0.f,0.f,0.f,0.f};
    MM6G(wf0, nt, acc)
    int col = nt*16 + (lane&15);
    #pragma unroll
    for (int v=0; v<4; v++){
      int n = nb + mb + ((lane>>4)<<2) + v;
      if (n < N) nout[(long)n*64 + col] = b16(acc[v]);
    }
  }
}

// node += sp(agg@nl2^T+b2)@nl3^T+b3; optionally nnb = bf16(node_new @ cw1_next^T)
template<bool PRODUCE_NN>
__global__ __launch_bounds__(256) void node_update8_kernel(float* __restrict__ node,
                                                           const float* __restrict__ agg,
                                                           const bf16x8* __restrict__ wfA, // nl2 frags
                                                           const float* __restrict__ nl2_b,
                                                           const bf16x8* __restrict__ wfB, // nl3 frags
                                                           const float* __restrict__ nl3_b,
                                                           const bf16x8* __restrict__ wfC, // cw1_next
                                                           unsigned short* __restrict__ nout, int N){
  __shared__ __align__(16) char XP[16384];
  char *XH = XP, *XLo = XP + 8192;
  int tid = threadIdx.x, lane = tid & 63, wv = tid >> 6;
  int nb = blockIdx.x*64, mb = wv*16;
  // stage agg rows (wave-local)
  #pragma unroll
  for (int t=0;t<16;t++){
    int row = mb + t, n = nb + row;
    float v = (n < N) ? agg[(long)n*64 + lane] : 0.f;
    stx(XH, XLo, row, lane, v);
  }
  __syncthreads();
  // matmul1: S = sp(X @ nl2^T + b2) -> back into X panels (own rows)
  {
    LDA(XH, XLo)
    #pragma unroll
    for (int nt=0; nt<4; nt++){
      float bb = nl2_b[nt*16 + (lane&15)];
      f32x4 acc = {bb,bb,bb,bb};
      MM6G(wfA, nt, acc)
      int col = nt*16 + (lane&15);
      #pragma unroll
      for (int v=0; v<4; v++){
        int row = mb + ((lane>>4)<<2) + v;
        stx(XH, XLo, row, col, sp_f(acc[v]));
      }
    }
  }
  // matmul2: node_new = node + S @ nl3^T + b3 -> node (f32) and X panels
  {
    LDA(XH, XLo)
    #pragma unroll
    for (int nt=0; nt<4; nt++){
      float bb = nl3_b[nt*16 + (lane&15)];
      f32x4 acc = {bb,bb,bb,bb};
      MM6G(wfB, nt, acc)
      int col = nt*16 + (lane&15);
      #pragma unroll
      for (int v=0; v<4; v++){
        int row = mb + ((lane>>4)<<2) + v;
        int n = nb + row;
        float nv = 0.f;
        if (n < N){
          long g = (long)n*64 + col;
          nv = node[g] + acc[v];
          node[g] = nv;
        }
        stx(XH, XLo, row, col, nv);
      }
    }
  }
  if (PRODUCE_NN){
    LDA(XH, XLo)
    #pragma unroll
    for (int nt=0; nt<4; nt++){
      f32x4 acc = {0.f,0.f,0.f,0.f};
      MM6G(wfC, nt, acc)
      int col = nt*16 + (lane&15);
      #pragma unroll
      for (int v=0; v<4; v++){
        int n = nb + mb + ((lane>>4)<<2) + v;
        if (n < N) nout[(long)n*64 + col] = b16(acc[v]);
      }
    }
  }
}

// gather-aggregate v2: wave = 1 dst node (readfirstlane -> SGPR), lane = feature.
// Edge stream via SCALAR loads (s_load_dwordx8 batches); idx/src extraction and
// row-pointer math on the SALU pipe; VALU per edge = 2 gathers + 2 shl + 1 fma.
__global__ __launch_bounds__(256) void agg_kernel(const unsigned int* __restrict__ csr,
                                                  const int* __restrict__ offs,
                                                  const unsigned short* __restrict__ tab,  // [TABP][64] bf16
                                                  const unsigned short* __restrict__ nnb,  // bf16 bits
                                                  float* __restrict__ agg, int N){
  int n = __builtin_amdgcn_readfirstlane(blockIdx.x*4 + (threadIdx.x >> 6));
  int lane = threadIdx.x & 63;
  if (n >= N) return;
  int beg = offs[n], end = offs[n+1];          // uniform -> s_load
  float acc0 = 0.f, acc1 = 0.f;

#define EDGE(P, ACC) { \
    const unsigned short* tr = tab + (((P) & 0xFFFFu) << 6);   /* SALU ptr math */ \
    const unsigned short* nr = nnb + (((P) >> 16) << 6); \
    float a_  = __uint_as_float(((unsigned int)tr[lane]) << 16); \
    float nn_ = __uint_as_float(((unsigned int)nr[lane]) << 16); \
    ACC = fmaf(nn_, a_, ACC); }

  int c = beg;
  for (; c + 8 <= end; c += 8){
    unsigned p0 = csr[c+0], p1 = csr[c+1], p2 = csr[c+2], p3 = csr[c+3];
    unsigned p4 = csr[c+4], p5 = csr[c+5], p6 = csr[c+6], p7 = csr[c+7];
    EDGE(p0, acc0) EDGE(p1, acc1) EDGE(p2, acc0) EDGE(p3, acc1)
    EDGE(p4, acc0) EDGE(p5, acc1) EDGE(p6, acc0) EDGE(p7, acc1)
  }
  for (; c < end; c++){
    unsigned p = csr[c];
    EDGE(p, acc0)
  }
#undef EDGE
  agg[(long)n*64 + lane] = acc0 + acc1;
}

// ---------------- heads ----------------

__global__ __launch_bounds__(256) void node_head_kernel(const float* __restrict__ node,
                                                        const int* __restrict__ nidx,
                                                        const float* __restrict__ nt1t,  // [64][32]
                                                        const float* __restrict__ nt1_b,
                                                        const float* __restrict__ nt2_w, // [3][32]
                                                        const float* __restrict__ nt2_b,
                                                        float* __restrict__ out, int NSEL){
  int r = __builtin_amdgcn_readfirstlane(blockIdx.x*4 + (threadIdx.x>>6));
  int lane = threadIdx.x & 63;
  if (r >= NSEL) return;
  long n = nidx[r];
  const float* x = node + n*64;                    // uniform -> s_loads
  float u = 0.f;
  if (lane < 32){
    u = nt1_b[lane];
    #pragma unroll
    for (int k=0;k<DIM;k++) u += x[k]*nt1t[k*32 + lane];
  }
  #pragma unroll
  for (int q=0;q<3;q++){
    float v = (lane < 32) ? u*nt2_w[q*32 + lane] : 0.f;
    #pragma unroll
    for (int o=32;o>=1;o>>=1) v += __shfl_xor(v, o);
    if (lane == 0) out[(long)r*3 + q] = nt2_b[q] + v;
  }
}

__global__ __launch_bounds__(256) void edge_head_kernel(const float* __restrict__ node,
                                                        const int* __restrict__ sidx,
                                                        const int* __restrict__ tidx,
                                                        const float* __restrict__ et1t, // [128][64]
                                                        const float* __restrict__ et1_b,
                                                        const float* __restrict__ et2_w,// [5][64]
                                                        const float* __restrict__ et2_b,
                                                        float* __restrict__ out, int ESEL){
  int wid = threadIdx.x >> 6, lane = threadIdx.x & 63;
  int r0 = (blockIdx.x*4 + wid)*4;
  if (r0 >= ESEL) return;
  float xs[4], xt[4], acc[4];
  #pragma unroll
  for (int i=0;i<4;i++){
    int r = r0+i < ESEL ? r0+i : ESEL-1;
    long s = sidx[r], t = tidx[r];
    xs[i] = node[s*64 + lane];
    xt[i] = node[t*64 + lane];
    acc[i] = et1_b[lane];
  }
  #pragma unroll 16
  for (int k=0;k<DIM;k++){
    float w1 = et1t[k*64 + lane];
    float w2 = et1t[(64+k)*64 + lane];
    #pragma unroll
    for (int i=0;i<4;i++){
      acc[i] = fmaf(rdl(xs[i], k), w1, acc[i]);
      acc[i] = fmaf(rdl(xt[i], k), w2, acc[i]);
    }
  }
  #pragma unroll
  for (int i=0;i<4;i++){
    if (r0+i >= ESEL) break;
    #pragma unroll
    for (int q=0;q<5;q++){
      float v = acc[i]*et2_w[q*64 + lane];
      #pragma unroll
      for (int o=32;o>=1;o>>=1) v += __shfl_xor(v, o);
      if (lane == 0) out[(long)(r0+i)*5 + q] = et2_b[q] + v;
    }
  }
}

// ---------------- launch ----------------

extern "C" void kernel_launch(void* const* d_in, const int* in_sizes, int n_in,
                              void* d_out, int out_size, void* d_ws, size_t ws_size,
                              hipStream_t stream){
  const float* emb      = (const float*)d_in[0];
  const float* dist     = (const float*)d_in[1];
  const float* edge_mask= (const float*)d_in[2];
  const float* conv_w1  = (const float*)d_in[3];
  const float* cf_w1    = (const float*)d_in[4];
  const float* cf_b1    = (const float*)d_in[5];
  const float* cf_w2    = (const float*)d_in[6];
  const float* cf_b2    = (const float*)d_in[7];
  const float* nl2_w    = (const float*)d_in[8];
  const float* nl2_b    = (const float*)d_in[9];
  const float* nl3_w    = (const float*)d_in[10];
  const float* nl3_b    = (const float*)d_in[11];
  const float* nt1_w    = (const float*)d_in[12];
  const float* nt1_b    = (const float*)d_in[13];
  const float* nt2_w    = (const float*)d_in[14];
  const float* nt2_b    = (const float*)d_in[15];
  const float* et1_w    = (const float*)d_in[16];
  const float* et1_b    = (const float*)d_in[17];
  const float* et2_w    = (const float*)d_in[18];
  const float* et2_b    = (const float*)d_in[19];
  const int* node_type  = (const int*)d_in[20];
  const int* src        = (const int*)d_in[21];
  const int* dst        = (const int*)d_in[22];
  const int* sel        = (const int*)d_in[23];
  const int* node_index = (const int*)d_in[24];
  const int* source_index = (const int*)d_in[25];
  const int* target_index = (const int*)d_in[26];

  int E    = in_sizes[1];
  int N    = in_sizes[20];
  int K    = in_sizes[23];
  int NSEL = in_sizes[24];
  int ESEL = in_sizes[25];

  int NB  = (N + 127) >> 7;           // buckets of 128 nodes
  int FW  = (E + 31) >> 5;            // flag words
  int nbE = (E + EPB - 1) / EPB;      // CSR-build blocks

  size_t N64 = (size_t)N*64;
  // bbuf (E u64) first for 8B alignment; agg aliases it (lifetimes disjoint)
  unsigned long long* bbuf = (unsigned long long*)d_ws;
  float* agg = (float*)d_ws;
  size_t aggsz = ((size_t)2*E > N64) ? (size_t)2*E : N64;   // float units
  float* p = (float*)d_ws + aggsz;
  float* node     = p; p += N64;
  unsigned short* nnb = (unsigned short*)p; p += N64/2;     // bf16 new_node
  float* w2t      = p; p += 3*4096;
  float* et1t     = p; p += 128*64;
  float* nt1t     = p; p += 64*32;
  float* w1t      = p; p += 3*NC*DIM;
  bf16x8* wfrag   = (bf16x8*)p; p += 9*16*64*4;             // 144KB fragment tables
  __hip_bfloat16* tabb = (__hip_bfloat16*)p; p += (size_t)3*TABP*DIM/2;
  unsigned int* csr      = (unsigned int*)p; p += E;
  unsigned int* flagbits = (unsigned int*)p; p += FW;
  unsigned int* gbcnt    = (unsigned int*)p; p += NB;
  unsigned int* bscan    = (unsigned int*)p; p += NB+1;
  unsigned int* gcursor  = (unsigned int*)p; p += NB;
  int* offs              = (int*)p; p += N+1;

  // CSR build: two-level LDS counting sort
  hipMemsetAsync(gbcnt, 0, (size_t)NB*sizeof(int), stream);
  bhist_kernel<<<nbE, 256, 0, stream>>>(dst, gbcnt, flagbits, E, NB, FW);
  sel_mark_kernel<<<(K+255)/256, 256, 0, stream>>>(sel, flagbits, K);
  prep_transpose_kernel<<<48, 256, 0, stream>>>(cf_w2, et1_w, nt1_w, cf_w1,
                                                w2t, et1t, nt1t, w1t);
  wprep2_kernel<<<18, 256, 0, stream>>>(conv_w1, nl2_w, nl3_w, wfrag);
  bscan_kernel<<<1, NBMAX, 0, stream>>>(gbcnt, bscan, gcursor, offs, NB, N, E);
  passA_kernel<<<nbE, 256, 0, stream>>>(dst, src, dist, flagbits, gcursor, bbuf, E, NB);
  passB_kernel<<<NB, 256, 0, stream>>>(bbuf, bscan, offs, csr, N);
  // filter tables (3 layers, wave=row, nearest-neighbor bf16)
  table_kernel<<<(3*TABP+3)/4, 256, 0, stream>>>(edge_mask, w1t, cf_b1, w2t, cf_b2, tabb);

  int nbP  = (N+63)/64;    // node-panel blocks (64 nodes/block, 4 waves)
  int nb_agg = (N+3)/4;    // 4 waves/block x 1 node/wave
  node_init8_kernel<<<nbP, 256, 0, stream>>>(emb, node_type, wfrag, node, nnb, N);
  for (int l=0;l<3;l++){
    agg_kernel<<<nb_agg, 256, 0, stream>>>(csr, offs,
        (const unsigned short*)(tabb + (size_t)l*TABP*DIM), nnb, agg, N);
    if (l < 2)
      node_update8_kernel<true><<<nbP, 256, 0, stream>>>(node, agg,
          wfrag + (3+l)*16*64, nl2_b + l*64,
          wfrag + (6+l)*16*64, nl3_b + l*64,
          wfrag + (1+l)*16*64, nnb, N);
    else
      node_update8_kernel<false><<<nbP, 256, 0, stream>>>(node, agg,
          wfrag + (3+l)*16*64, nl2_b + l*64,
          wfrag + (6+l)*16*64, nl3_b + l*64,
          nullptr, nullptr, N);
  }

  node_head_kernel<<<(NSEL+3)/4, 256, 0, stream>>>(node, node_index,
      nt1t, nt1_b, nt2_w, nt2_b, (float*)d_out, NSEL);
  edge_head_kernel<<<(ESEL+15)/16, 256, 0, stream>>>(node, source_index, target_index,
      et1t, et1_b, et2_w, et2_b, (float*)d_out + (size_t)NSEL*3, ESEL);
}

// Round 18
// 296.821 us; speedup vs baseline: 7.3639x; 1.0042x over previous
//
#include <hip/hip_runtime.h>
#include <hip/hip_bf16.h>

#define DIM 64
#define NC 50
#define TABN 4096
#define TABP (TABN + 2)   // rows 0..4096 = h at p*5/4096, row 4097 = mask row
#define EPB 4096          // edges per block in CSR build
#define NBMAX 512         // max buckets (N <= 65536)

typedef short bf16x8 __attribute__((ext_vector_type(8)));
typedef float f32x4  __attribute__((ext_vector_type(4)));
#define MFMA(a,b,c) __builtin_amdgcn_mfma_f32_16x16x32_bf16(a,b,c,0,0,0)

__device__ __forceinline__ float sp_f(float x){
  // torch Softplus(beta=0.5, threshold=14): 2*log(1+exp(0.5x)), linear when 0.5*x>14
  float e = __expf(0.5f*x);
  float s = 2.0f*__logf(1.0f+e);
  return x > 28.0f ? x : s;
}

__device__ __forceinline__ float rdl(float v, int l){
  return __int_as_float(__builtin_amdgcn_readlane(__float_as_int(v), l));
}

__device__ __forceinline__ unsigned short b16(float x){
  __hip_bfloat16 h = __float2bfloat16(x);
  return __builtin_bit_cast(unsigned short, h);
}

// split x into hi + lo bf16 (lo = bf16(x - float(hi))) -> ~fp32 via 3-term MFMA
__device__ __forceinline__ void wsplit(float x, unsigned short& h, unsigned short& l){
  h = b16(x);
  float hf = __uint_as_float(((unsigned int)h) << 16);
  l = b16(x - hf);
}

// ---------------- CSR build: two-level LDS counting sort ----------------

__global__ __launch_bounds__(256) void bhist_kernel(const int* __restrict__ dst,
                                                    unsigned int* __restrict__ gbcnt,
                                                    int E, int NB){
  __shared__ unsigned int cnt[NBMAX];
  int tid = threadIdx.x;
  for (int b=tid; b<NB; b+=256) cnt[b] = 0;
  __syncthreads();
  int e0 = blockIdx.x*EPB, eend = min(e0+EPB, E);
  for (int e=e0+tid; e<eend; e+=256) atomicAdd(&cnt[dst[e]>>7], 1u);
  __syncthreads();
  for (int b=tid; b<NB; b+=256) if (cnt[b]) atomicAdd(&gbcnt[b], cnt[b]);
}

__global__ void sel_mark_kernel(const int* __restrict__ sel,
                                unsigned int* __restrict__ flagbits, int K){
  int id = blockIdx.x*256 + threadIdx.x;
  if (id < K){ int e = sel[id]; atomicOr(&flagbits[e>>5], 1u << (e&31)); }
}

__global__ __launch_bounds__(NBMAX) void bscan_kernel(const unsigned int* __restrict__ gbcnt,
                                                      unsigned int* __restrict__ bscan,
                                                      unsigned int* __restrict__ gcursor,
                                                      int* __restrict__ offs,
                                                      int NB, int N, int E){
  __shared__ unsigned int s[NBMAX];
  int tid = threadIdx.x;
  unsigned int v = (tid < NB) ? gbcnt[tid] : 0;
  s[tid] = v;
  __syncthreads();
  for (int off=1; off<NBMAX; off<<=1){
    unsigned int u = (tid >= off) ? s[tid-off] : 0;
    __syncthreads();
    s[tid] += u;
    __syncthreads();
  }
  unsigned int excl = s[tid] - v;
  if (tid < NB){ bscan[tid] = excl; gcursor[tid] = excl; }
  if (tid == NB-1) bscan[NB] = excl + v;
  if (tid == 0) offs[N] = E;
}

// bucket-scatter with LOCAL bucket-major reorder -> coalesced global writes.
__global__ __launch_bounds__(256) void passA_kernel(const int* __restrict__ dst,
                                                    const int* __restrict__ src,
                                                    const float* __restrict__ dist,
                                                    const unsigned int* __restrict__ flagbits,
                                                    unsigned int* __restrict__ gcursor,
                                                    unsigned long long* __restrict__ bbuf,
                                                    int E, int NB){
  __shared__ unsigned int cnt[NBMAX];     // counts -> local cursor
  __shared__ unsigned int gdst[NBMAX];    // chunkbase[b] - lexcl[b]
  __shared__ unsigned int wpart[4];
  __shared__ unsigned long long lbuf[EPB];
  int tid = threadIdx.x, lane = tid & 63, wv = tid >> 6;
  for (int b=tid; b<NB; b+=256) cnt[b] = 0;
  __syncthreads();
  int e0 = blockIdx.x*EPB;
  int m = E - e0; if (m > EPB) m = EPB;
  int dreg[16];
  #pragma unroll
  for (int i=0;i<16;i++){
    int li = tid + 256*i;
    dreg[i] = (li < m) ? dst[e0 + li] : -1;
    if (dreg[i] >= 0) atomicAdd(&cnt[dreg[i]>>7], 1u);
  }
  __syncthreads();
  // block exclusive scan over NB buckets (2 per thread) + chunk reservation
  int t2 = tid*2;
  unsigned c0 = (t2 < NB) ? cnt[t2] : 0;
  unsigned c1 = (t2+1 < NB) ? cnt[t2+1] : 0;
  unsigned pv = c0 + c1, x = pv;
  #pragma unroll
  for (int off=1; off<64; off<<=1){ unsigned u = __shfl_up(x, off); if (lane >= off) x += u; }
  if (lane == 63) wpart[wv] = x;
  __syncthreads();
  unsigned wb = 0;
  #pragma unroll
  for (int q=0;q<4;q++) wb += (q < wv) ? wpart[q] : 0;
  unsigned ex0 = wb + x - pv;
  unsigned ex1 = ex0 + c0;
  if (t2 < NB){
    unsigned gb = c0 ? atomicAdd(&gcursor[t2], c0) : 0u;
    gdst[t2] = gb - ex0;
    cnt[t2]  = ex0;                      // local cursor
  }
  if (t2+1 < NB){
    unsigned gb = c1 ? atomicAdd(&gcursor[t2+1], c1) : 0u;
    gdst[t2+1] = gb - ex1;
    cnt[t2+1]  = ex1;
  }
  __syncthreads();
  // local scatter (bucket-major); stash full dst in hi for phase 4
  #pragma unroll
  for (int i=0;i<16;i++){
    if (dreg[i] < 0) continue;
    int li = tid + 256*i;
    int e = e0 + li;
    int d = dreg[i];
    unsigned pos = atomicAdd(&cnt[d>>7], 1u);
    float tq = fminf(dist[e], 5.f) * ((float)TABN/5.0f);
    int idx = (int)(tq + 0.5f); if (idx > TABN) idx = TABN;   // nearest grid point
    if ((flagbits[e>>5] >> (e&31)) & 1u) idx = TABN+1;        // mask row
    unsigned lo = ((unsigned int)src[e] << 16) | (unsigned int)idx;
    lbuf[pos] = ((unsigned long long)(unsigned int)d << 32) | lo;
  }
  __syncthreads();
  // coalesced write-out
  for (int i=tid; i<m; i+=256){
    unsigned long long v = lbuf[i];
    unsigned d = (unsigned int)(v >> 32);
    unsigned addr = gdst[d>>7] + (unsigned int)i;   // = chunkbase + (i - lexcl)
    bbuf[addr] = (v & 0xFFFFFFFFull) | ((unsigned long long)(d & 127u) << 32);
  }
}

__global__ __launch_bounds__(256) void passB_kernel(const unsigned long long* __restrict__ bbuf,
                                                    const unsigned int* __restrict__ bscan,
                                                    int* __restrict__ offs,
                                                    unsigned int* __restrict__ csr,
                                                    int N){
  __shared__ unsigned int cnt[128];
  __shared__ unsigned int excl[128];
  int b = blockIdx.x, tid = threadIdx.x;
  unsigned int s0 = bscan[b];
  int m = (int)(bscan[b+1] - s0);
  if (tid < 128) cnt[tid] = 0;
  __syncthreads();
  for (int i=tid; i<m; i+=256)
    atomicAdd(&cnt[(unsigned int)(bbuf[s0+i] >> 32)], 1u);
  __syncthreads();
  if (tid < 128) excl[tid] = cnt[tid];
  __syncthreads();
  for (int off=1; off<128; off<<=1){
    unsigned int v = (tid < 128 && tid >= off) ? excl[tid-off] : 0;
    __syncthreads();
    if (tid < 128) excl[tid] += v;
    __syncthreads();
  }
  int node0 = b << 7;
  if (tid < 128){
    unsigned int ex = excl[tid] - cnt[tid];    // exclusive
    int n = node0 + tid;
    if (n < N) offs[n] = (int)(s0 + ex);
    excl[tid] = ex;
    cnt[tid] = 0;                              // reuse as cursor
  }
  __syncthreads();
  for (int i=tid; i<m; i+=256){
    unsigned long long v = bbuf[s0+i];
    unsigned int hi = (unsigned int)(v >> 32);
    unsigned int loc = atomicAdd(&cnt[hi], 1u);
    csr[s0 + excl[hi] + loc] = (unsigned int)v;
  }
}

// ---------------- fused prep: transposes + split weight fragment tables ----------

__global__ void prep_all_kernel(const float* __restrict__ cf_w2,
                                const float* __restrict__ et1_w,
                                const float* __restrict__ nt1_w,
                                const float* __restrict__ cf_w1,
                                const float* __restrict__ cw1,
                                const float* __restrict__ nl2,
                                const float* __restrict__ nl3,
                                float* __restrict__ w2t,
                                float* __restrict__ et1t,
                                float* __restrict__ nt1t,
                                float* __restrict__ w1t,
                                bf16x8* __restrict__ wfrag){
  int id = blockIdx.x*256 + threadIdx.x;
  if (id < 3*4096){
    int i = id >> 12, r = id & 4095;
    int k = r >> 6, j = r & 63;
    w2t[id]  = cf_w2[i*4096 + j*64 + k];
  }
  if (id < 128*64){
    int k = id >> 6, j = id & 63;
    et1t[id] = et1_w[j*128 + k];   // et1_w is [64][128]
  }
  if (id < 64*32){
    int k = id >> 5, j = id & 31;
    nt1t[id] = nt1_w[j*64 + k];    // nt1_w is [32][64]
  }
  if (id < 3*NC*DIM){              // cf_w1 [3][64][50] -> w1t [3][50][64]
    int l = id / (NC*DIM);
    int r = id - l*(NC*DIM);
    int m = r >> 6, k = r & 63;
    w1t[id] = cf_w1[l*DIM*NC + k*NC + m];
  }
  if (id < 9*8*64){                // wfrag: per-lane MFMA B-fragments (hi/lo)
    int lane = id & 63;
    int f8 = (id >> 6) & 7;        // nt*2 + ks
    int m  = id >> 9;
    int nt = f8 >> 1, ks = f8 & 1;
    const float* W = (m < 3) ? (cw1 + m*4096)
                   : (m < 6) ? (nl2 + (m-3)*4096)
                             : (nl3 + (m-6)*4096);
    int j  = nt*16 + (lane & 15);
    int k0 = ks*32 + (lane >> 4)*8;
    bf16x8 vh, vl;
    #pragma unroll
    for (int u=0;u<8;u++){
      unsigned short h,l;
      wsplit(W[j*64 + k0 + u], h, l);
      vh[u] = (short)h; vl[u] = (short)l;
    }
    int fb = m*16 + nt*4 + ks*2;
    wfrag[(fb+0)*64 + lane] = vh;
    wfrag[(fb+1)*64 + lane] = vl;
  }
}

// ---------------- filter table (bf16, nearest), wave = row, lane = feature ----------

__global__ __launch_bounds__(256) void table_kernel(const float* __restrict__ edge_mask,
                                                    const float* __restrict__ w1t,   // [3][50][64]
                                                    const float* __restrict__ cf_b1,
                                                    const float* __restrict__ w2t,   // [3][64][64]
                                                    const float* __restrict__ cf_b2,
                                                    __hip_bfloat16* __restrict__ tabb){
  int row = blockIdx.x*4 + (threadIdx.x >> 6);
  if (row >= 3*TABP) return;
  int l = row / TABP, p = row - l*TABP;
  int lane = threadIdx.x & 63;
  float rbfv = 0.f;
  if (lane < NC){
    if (p == TABN+1) rbfv = edge_mask[lane];
    else {
      float d = (float)p * (5.0f/(float)TABN);
      float c = (lane == NC-1) ? 5.0f : (float)((double)lane * (5.0/49.0));
      float df = d - c;
      rbfv = __expf((float)(-1.0/(5.0/49.0)) * df * df);
    }
  }
  const float* W1 = w1t + l*NC*DIM;
  float t = cf_b1[l*DIM + lane];
  #pragma unroll 10
  for (int m=0;m<NC;m++)
    t = fmaf(rdl(rbfv, m), W1[m*64 + lane], t);
  float su = sp_f(t);
  const float* W2 = w2t + l*DIM*DIM;
  float h = cf_b2[l*DIM + lane];
  #pragma unroll 16
  for (int k=0;k<DIM;k++)
    h = fmaf(rdl(su, k), W2[k*64 + lane], h);
  tabb[((size_t)l*TABP + p)*DIM + lane] = __float2bfloat16(h);
}

// ---------------- node-side v8: MFMA, weights from global fragment tables --------

__device__ __forceinline__ bf16x8 ldfrag(const char* base, int rowbase, int ks, int lane){
  int r = lane & 15;
  int off = (ks<<6) + ((lane>>4)<<4);
  return *(const bf16x8*)(base + (rowbase + r)*128 + (off ^ ((r & 7)<<4)));
}

__device__ __forceinline__ void stx(char* XH, char* XLo, int row, int col, float v){
  unsigned short h,l;
  wsplit(v, h, l);
  int off = row*128 + ((col*2) ^ ((row&7)<<4));
  *(unsigned short*)(XH + off) = h;
  *(unsigned short*)(XLo + off) = l;
}

#define MM6G(WF, NT, ACC) \
  { ACC = MFMA(ah0, (WF)[((NT)*4+0)*64 + lane], ACC); \
    ACC = MFMA(ah1, (WF)[((NT)*4+2)*64 + lane], ACC); \
    ACC = MFMA(ah0, (WF)[((NT)*4+1)*64 + lane], ACC); \
    ACC = MFMA(ah1, (WF)[((NT)*4+3)*64 + lane], ACC); \
    ACC = MFMA(al0, (WF)[((NT)*4+0)*64 + lane], ACC); \
    ACC = MFMA(al1, (WF)[((NT)*4+2)*64 + lane], ACC); }

#define LDA(XH_, XLo_) \
  bf16x8 ah0 = ldfrag(XH_, mb, 0, lane), ah1 = ldfrag(XH_, mb, 1, lane); \
  bf16x8 al0 = ldfrag(XLo_, mb, 0, lane), al1 = ldfrag(XLo_, mb, 1, lane);

// node = emb[node_type]; nnb = bf16(node @ conv_w1[0]^T)
__global__ __launch_bounds__(256) void node_init8_kernel(const float* __restrict__ emb,
                                                         const int* __restrict__ node_type,
                                                         const bf16x8* __restrict__ wf0,
                                                         float* __restrict__ node,
                                                         unsigned short* __restrict__ nout, int N){
  __shared__ __align__(16) char XP[16384];
  char *XH = XP, *XLo = XP + 8192;
  int tid = threadIdx.x, lane = tid & 63, wv = tid >> 6;
  int nb = blockIdx.x*64, mb = wv*16;
  #pragma unroll
  for (int t=0;t<16;t++){
    int row = mb + t, n = nb + row;
    int ty = (n < N) ? node_type[n] : 0;
    float v = emb[(long)ty*64 + lane];
    if (n < N) node[(long)n*64 + lane] = v;
    stx(XH, XLo, row, lane, v);
  }
  __syncthreads();
  LDA(XH, XLo)
  #pragma unroll
  for (int nt=0; nt<4; nt++){
    f32x4 acc = {0.f,0.f,0.f,0.f};
    MM6G(wf0, nt, acc)
    int col = nt*16 + (lane&15);
    #pragma unroll
    for (int v=0; v<4; v++){
      int n = nb + mb + ((lane>>4)<<2) + v;
      if (n < N) nout[(long)n*64 + col] = b16(acc[v]);
    }
  }
}

// node += sp(agg@nl2^T+b2)@nl3^T+b3; optionally nnb = bf16(node_new @ cw1_next^T)
template<bool PRODUCE_NN>
__global__ __launch_bounds__(256) void node_update8_kernel(float* __restrict__ node,
                                                           const float* __restrict__ agg,
                                                           const bf16x8* __restrict__ wfA, // nl2 frags
                                                           const float* __restrict__ nl2_b,
                                                           const bf16x8* __restrict__ wfB, // nl3 frags
                                                           const float* __restrict__ nl3_b,
                                                           const bf16x8* __restrict__ wfC, // cw1_next
                                                           unsigned short* __restrict__ nout, int N){
  __shared__ __align__(16) char XP[16384];
  char *XH = XP, *XLo = XP + 8192;
  int tid = threadIdx.x, lane = tid & 63, wv = tid >> 6;
  int nb = blockIdx.x*64, mb = wv*16;
  // stage agg rows (wave-local)
  #pragma unroll
  for (int t=0;t<16;t++){
    int row = mb + t, n = nb + row;
    float v = (n < N) ? agg[(long)n*64 + lane] : 0.f;
    stx(XH, XLo, row, lane, v);
  }
  __syncthreads();
  // matmul1: S = sp(X @ nl2^T + b2) -> back into X panels (own rows)
  {
    LDA(XH, XLo)
    #pragma unroll
    for (int nt=0; nt<4; nt++){
      float bb = nl2_b[nt*16 + (lane&15)];
      f32x4 acc = {bb,bb,bb,bb};
      MM6G(wfA, nt, acc)
      int col = nt*16 + (lane&15);
      #pragma unroll
      for (int v=0; v<4; v++){
        int row = mb + ((lane>>4)<<2) + v;
        stx(XH, XLo, row, col, sp_f(acc[v]));
      }
    }
  }
  // matmul2: node_new = node + S @ nl3^T + b3 -> node (f32) and X panels
  {
    LDA(XH, XLo)
    #pragma unroll
    for (int nt=0; nt<4; nt++){
      float bb = nl3_b[nt*16 + (lane&15)];
      f32x4 acc = {bb,bb,bb,bb};
      MM6G(wfB, nt, acc)
      int col = nt*16 + (lane&15);
      #pragma unroll
      for (int v=0; v<4; v++){
        int row = mb + ((lane>>4)<<2) + v;
        int n = nb + row;
        float nv = 0.f;
        if (n < N){
          long g = (long)n*64 + col;
          nv = node[g] + acc[v];
          node[g] = nv;
        }
        stx(XH, XLo, row, col, nv);
      }
    }
  }
  if (PRODUCE_NN){
    LDA(XH, XLo)
    #pragma unroll
    for (int nt=0; nt<4; nt++){
      f32x4 acc = {0.f,0.f,0.f,0.f};
      MM6G(wfC, nt, acc)
      int col = nt*16 + (lane&15);
      #pragma unroll
      for (int v=0; v<4; v++){
        int n = nb + mb + ((lane>>4)<<2) + v;
        if (n < N) nout[(long)n*64 + col] = b16(acc[v]);
      }
    }
  }
}

// gather-aggregate v2: wave = 1 dst node (readfirstlane -> SGPR), lane = feature.
__global__ __launch_bounds__(256) void agg_kernel(const unsigned int* __restrict__ csr,
                                                  const int* __restrict__ offs,
                                                  const unsigned short* __restrict__ tab,  // [TABP][64] bf16
                                                  const unsigned short* __restrict__ nnb,  // bf16 bits
                                                  float* __restrict__ agg, int N){
  int n = __builtin_amdgcn_readfirstlane(blockIdx.x*4 + (threadIdx.x >> 6));
  int lane = threadIdx.x & 63;
  if (n >= N) return;
  int beg = offs[n], end = offs[n+1];          // uniform -> s_load
  float acc0 = 0.f, acc1 = 0.f;

#define EDGE(P, ACC) { \
    const unsigned short* tr = tab + (((P) & 0xFFFFu) << 6);   /* SALU ptr math */ \
    const unsigned short* nr = nnb + (((P) >> 16) << 6); \
    float a_  = __uint_as_float(((unsigned int)tr[lane]) << 16); \
    float nn_ = __uint_as_float(((unsigned int)nr[lane]) << 16); \
    ACC = fmaf(nn_, a_, ACC); }

  int c = beg;
  for (; c + 8 <= end; c += 8){
    unsigned p0 = csr[c+0], p1 = csr[c+1], p2 = csr[c+2], p3 = csr[c+3];
    unsigned p4 = csr[c+4], p5 = csr[c+5], p6 = csr[c+6], p7 = csr[c+7];
    EDGE(p0, acc0) EDGE(p1, acc1) EDGE(p2, acc0) EDGE(p3, acc1)
    EDGE(p4, acc0) EDGE(p5, acc1) EDGE(p6, acc0) EDGE(p7, acc1)
  }
  for (; c < end; c++){
    unsigned p = csr[c];
    EDGE(p, acc0)
  }
#undef EDGE
  agg[(long)n*64 + lane] = acc0 + acc1;
}

// ---------------- fused heads ----------------

__global__ __launch_bounds__(256) void heads_kernel(const float* __restrict__ node,
                                                    const int* __restrict__ nidx,
                                                    const float* __restrict__ nt1t,  // [64][32]
                                                    const float* __restrict__ nt1_b,
                                                    const float* __restrict__ nt2_w, // [3][32]
                                                    const float* __restrict__ nt2_b,
                                                    float* __restrict__ outN, int NSEL, int nbN,
                                                    const int* __restrict__ sidx,
                                                    const int* __restrict__ tidx,
                                                    const float* __restrict__ et1t, // [128][64]
                                                    const float* __restrict__ et1_b,
                                                    const float* __restrict__ et2_w,// [5][64]
                                                    const float* __restrict__ et2_b,
                                                    float* __restrict__ outE, int ESEL){
  int lane = threadIdx.x & 63;
  if ((int)blockIdx.x < nbN){
    // ---- node head: wave = 1 row ----
    int r = __builtin_amdgcn_readfirstlane(blockIdx.x*4 + (threadIdx.x>>6));
    if (r >= NSEL) return;
    long n = nidx[r];
    const float* x = node + n*64;                  // uniform -> s_loads
    float u = 0.f;
    if (lane < 32){
      u = nt1_b[lane];
      #pragma unroll
      for (int k=0;k<DIM;k++) u += x[k]*nt1t[k*32 + lane];
    }
    #pragma unroll
    for (int q=0;q<3;q++){
      float v = (lane < 32) ? u*nt2_w[q*32 + lane] : 0.f;
      #pragma unroll
      for (int o=32;o>=1;o>>=1) v += __shfl_xor(v, o);
      if (lane == 0) outN[(long)r*3 + q] = nt2_b[q] + v;
    }
  } else {
    // ---- edge head: wave = 4 rows ----
    int wid = threadIdx.x >> 6;
    int r0 = (((int)blockIdx.x - nbN)*4 + wid)*4;
    if (r0 >= ESEL) return;
    float xs[4], xt[4], acc[4];
    #pragma unroll
    for (int i=0;i<4;i++){
      int r = r0+i < ESEL ? r0+i : ESEL-1;
      long s = sidx[r], t = tidx[r];
      xs[i] = node[s*64 + lane];
      xt[i] = node[t*64 + lane];
      acc[i] = et1_b[lane];
    }
    #pragma unroll 16
    for (int k=0;k<DIM;k++){
      float w1 = et1t[k*64 + lane];
      float w2 = et1t[(64+k)*64 + lane];
      #pragma unroll
      for (int i=0;i<4;i++){
        acc[i] = fmaf(rdl(xs[i], k), w1, acc[i]);
        acc[i] = fmaf(rdl(xt[i], k), w2, acc[i]);
      }
    }
    #pragma unroll
    for (int i=0;i<4;i++){
      if (r0+i >= ESEL) break;
      #pragma unroll
      for (int q=0;q<5;q++){
        float v = acc[i]*et2_w[q*64 + lane];
        #pragma unroll
        for (int o=32;o>=1;o>>=1) v += __shfl_xor(v, o);
        if (lane == 0) outE[(long)(r0+i)*5 + q] = et2_b[q] + v;
      }
    }
  }
}

// ---------------- launch ----------------

extern "C" void kernel_launch(void* const* d_in, const int* in_sizes, int n_in,
                              void* d_out, int out_size, void* d_ws, size_t ws_size,
                              hipStream_t stream){
  const float* emb      = (const float*)d_in[0];
  const float* dist     = (const float*)d_in[1];
  const float* edge_mask= (const float*)d_in[2];
  const float* conv_w1  = (const float*)d_in[3];
  const float* cf_w1    = (const float*)d_in[4];
  const float* cf_b1    = (const float*)d_in[5];
  const float* cf_w2    = (const float*)d_in[6];
  const float* cf_b2    = (const float*)d_in[7];
  const float* nl2_w    = (const float*)d_in[8];
  const float* nl2_b    = (const float*)d_in[9];
  const float* nl3_w    = (const float*)d_in[10];
  const float* nl3_b    = (const float*)d_in[11];
  const float* nt1_w    = (const float*)d_in[12];
  const float* nt1_b    = (const float*)d_in[13];
  const float* nt2_w    = (const float*)d_in[14];
  const float* nt2_b    = (const float*)d_in[15];
  const float* et1_w    = (const float*)d_in[16];
  const float* et1_b    = (const float*)d_in[17];
  const float* et2_w    = (const float*)d_in[18];
  const float* et2_b    = (const float*)d_in[19];
  const int* node_type  = (const int*)d_in[20];
  const int* src        = (const int*)d_in[21];
  const int* dst        = (const int*)d_in[22];
  const int* sel        = (const int*)d_in[23];
  const int* node_index = (const int*)d_in[24];
  const int* source_index = (const int*)d_in[25];
  const int* target_index = (const int*)d_in[26];

  int E    = in_sizes[1];
  int N    = in_sizes[20];
  int K    = in_sizes[23];
  int NSEL = in_sizes[24];
  int ESEL = in_sizes[25];

  int NB  = (N + 127) >> 7;           // buckets of 128 nodes
  int FW  = (E + 31) >> 5;            // flag words
  int nbE = (E + EPB - 1) / EPB;      // CSR-build blocks

  size_t N64 = (size_t)N*64;
  // bbuf (E u64) first for 8B alignment; agg aliases it (lifetimes disjoint)
  unsigned long long* bbuf = (unsigned long long*)d_ws;
  float* agg = (float*)d_ws;
  size_t aggsz = ((size_t)2*E > N64) ? (size_t)2*E : N64;   // float units
  float* p = (float*)d_ws + aggsz;
  float* node     = p; p += N64;
  unsigned short* nnb = (unsigned short*)p; p += N64/2;     // bf16 new_node
  float* w2t      = p; p += 3*4096;
  float* et1t     = p; p += 128*64;
  float* nt1t     = p; p += 64*32;
  float* w1t      = p; p += 3*NC*DIM;
  bf16x8* wfrag   = (bf16x8*)p; p += 9*16*64*4;             // 144KB fragment tables
  __hip_bfloat16* tabb = (__hip_bfloat16*)p; p += (size_t)3*TABP*DIM/2;
  unsigned int* csr      = (unsigned int*)p; p += E;
  unsigned int* gbcnt    = (unsigned int*)p; p += NB;       // adjacent to flagbits:
  unsigned int* flagbits = (unsigned int*)p; p += FW;       //   one memset covers both
  unsigned int* bscan    = (unsigned int*)p; p += NB+1;
  unsigned int* gcursor  = (unsigned int*)p; p += NB;
  int* offs              = (int*)p; p += N+1;

  // CSR build: two-level LDS counting sort
  hipMemsetAsync(gbcnt, 0, (size_t)(NB + FW)*sizeof(int), stream);
  sel_mark_kernel<<<(K+255)/256, 256, 0, stream>>>(sel, flagbits, K);
  bhist_kernel<<<nbE, 256, 0, stream>>>(dst, gbcnt, E, NB);
  prep_all_kernel<<<48, 256, 0, stream>>>(cf_w2, et1_w, nt1_w, cf_w1,
                                          conv_w1, nl2_w, nl3_w,
                                          w2t, et1t, nt1t, w1t, wfrag);
  bscan_kernel<<<1, NBMAX, 0, stream>>>(gbcnt, bscan, gcursor, offs, NB, N, E);
  passA_kernel<<<nbE, 256, 0, stream>>>(dst, src, dist, flagbits, gcursor, bbuf, E, NB);
  passB_kernel<<<NB, 256, 0, stream>>>(bbuf, bscan, offs, csr, N);
  // filter tables (3 layers, wave=row, nearest-neighbor bf16)
  table_kernel<<<(3*TABP+3)/4, 256, 0, stream>>>(edge_mask, w1t, cf_b1, w2t, cf_b2, tabb);

  int nbP  = (N+63)/64;    // node-panel blocks (64 nodes/block, 4 waves)
  int nb_agg = (N+3)/4;    // 4 waves/block x 1 node/wave
  node_init8_kernel<<<nbP, 256, 0, stream>>>(emb, node_type, wfrag, node, nnb, N);
  for (int l=0;l<3;l++){
    agg_kernel<<<nb_agg, 256, 0, stream>>>(csr, offs,
        (const unsigned short*)(tabb + (size_t)l*TABP*DIM), nnb, agg, N);
    if (l < 2)
      node_update8_kernel<true><<<nbP, 256, 0, stream>>>(node, agg,
          wfrag + (3+l)*16*64, nl2_b + l*64,
          wfrag + (6+l)*16*64, nl3_b + l*64,
          wfrag + (1+l)*16*64, nnb, N);
    else
      node_update8_kernel<false><<<nbP, 256, 0, stream>>>(node, agg,
          wfrag + (3+l)*16*64, nl2_b + l*64,
          wfrag + (6+l)*16*64, nl3_b + l*64,
          nullptr, nullptr, N);
  }

  int nbN = (NSEL+3)/4;
  int nbEH = (ESEL+15)/16;
  heads_kernel<<<nbN + nbEH, 256, 0, stream>>>(node, node_index,
      nt1t, nt1_b, nt2_w, nt2_b, (float*)d_out, NSEL, nbN,
      source_index, target_index, et1t, et1_b, et2_w, et2_b,
      (float*)d_out + (size_t)NSEL*3, ESEL);
}

// Round 19
// 296.176 us; speedup vs baseline: 7.3799x; 1.0022x over previous
//
#include <hip/hip_runtime.h>
#include <hip/hip_bf16.h>

#define DIM 64
#define NC 50
#define TABN 4096
#define TABP (TABN + 2)   // rows 0..4096 = h at p*5/4096, row 4097 = mask row
#define EPB 4096          // edges per block in CSR build
#define NBMAX 512         // max buckets (N <= 65536)

typedef short bf16x8 __attribute__((ext_vector_type(8)));
typedef float f32x4  __attribute__((ext_vector_type(4)));
#define MFMA(a,b,c) __builtin_amdgcn_mfma_f32_16x16x32_bf16(a,b,c,0,0,0)

__device__ __forceinline__ float sp_f(float x){
  // torch Softplus(beta=0.5, threshold=14): 2*log(1+exp(0.5x)), linear when 0.5*x>14
  float e = __expf(0.5f*x);
  float s = 2.0f*__logf(1.0f+e);
  return x > 28.0f ? x : s;
}

__device__ __forceinline__ float rdl(float v, int l){
  return __int_as_float(__builtin_amdgcn_readlane(__float_as_int(v), l));
}

__device__ __forceinline__ unsigned short b16(float x){
  __hip_bfloat16 h = __float2bfloat16(x);
  return __builtin_bit_cast(unsigned short, h);
}

// split x into hi + lo bf16 (lo = bf16(x - float(hi))) -> ~fp32 via 3-term MFMA
__device__ __forceinline__ void wsplit(float x, unsigned short& h, unsigned short& l){
  h = b16(x);
  float hf = __uint_as_float(((unsigned int)h) << 16);
  l = b16(x - hf);
}

// ---------------- CSR build: two-level LDS counting sort ----------------

__global__ __launch_bounds__(256) void bhist_kernel(const int* __restrict__ dst,
                                                    unsigned int* __restrict__ gbcnt,
                                                    int E, int NB){
  __shared__ unsigned int cnt[NBMAX];
  int tid = threadIdx.x;
  for (int b=tid; b<NB; b+=256) cnt[b] = 0;
  __syncthreads();
  int e0 = blockIdx.x*EPB, eend = min(e0+EPB, E);
  for (int e=e0+tid; e<eend; e+=256) atomicAdd(&cnt[dst[e]>>7], 1u);
  __syncthreads();
  for (int b=tid; b<NB; b+=256) if (cnt[b]) atomicAdd(&gbcnt[b], cnt[b]);
}

__global__ void sel_mark_kernel(const int* __restrict__ sel,
                                unsigned int* __restrict__ flagbits, int K){
  int id = blockIdx.x*256 + threadIdx.x;
  if (id < K){ int e = sel[id]; atomicOr(&flagbits[e>>5], 1u << (e&31)); }
}

__global__ __launch_bounds__(NBMAX) void bscan_kernel(const unsigned int* __restrict__ gbcnt,
                                                      unsigned int* __restrict__ bscan,
                                                      unsigned int* __restrict__ gcursor,
                                                      int* __restrict__ offs,
                                                      int NB, int N, int E){
  __shared__ unsigned int s[NBMAX];
  int tid = threadIdx.x;
  unsigned int v = (tid < NB) ? gbcnt[tid] : 0;
  s[tid] = v;
  __syncthreads();
  for (int off=1; off<NBMAX; off<<=1){
    unsigned int u = (tid >= off) ? s[tid-off] : 0;
    __syncthreads();
    s[tid] += u;
    __syncthreads();
  }
  unsigned int excl = s[tid] - v;
  if (tid < NB){ bscan[tid] = excl; gcursor[tid] = excl; }
  if (tid == NB-1) bscan[NB] = excl + v;
  if (tid == 0) offs[N] = E;
}

// bucket-scatter with LOCAL bucket-major reorder -> coalesced global writes.
__global__ __launch_bounds__(256) void passA_kernel(const int* __restrict__ dst,
                                                    const int* __restrict__ src,
                                                    const float* __restrict__ dist,
                                                    const unsigned int* __restrict__ flagbits,
                                                    unsigned int* __restrict__ gcursor,
                                                    unsigned long long* __restrict__ bbuf,
                                                    int E, int NB){
  __shared__ unsigned int cnt[NBMAX];     // counts -> local cursor
  __shared__ unsigned int gdst[NBMAX];    // chunkbase[b] - lexcl[b]
  __shared__ unsigned int wpart[4];
  __shared__ unsigned long long lbuf[EPB];
  int tid = threadIdx.x, lane = tid & 63, wv = tid >> 6;
  for (int b=tid; b<NB; b+=256) cnt[b] = 0;
  __syncthreads();
  int e0 = blockIdx.x*EPB;
  int m = E - e0; if (m > EPB) m = EPB;
  int dreg[16];
  #pragma unroll
  for (int i=0;i<16;i++){
    int li = tid + 256*i;
    dreg[i] = (li < m) ? dst[e0 + li] : -1;
    if (dreg[i] >= 0) atomicAdd(&cnt[dreg[i]>>7], 1u);
  }
  __syncthreads();
  // block exclusive scan over NB buckets (2 per thread) + chunk reservation
  int t2 = tid*2;
  unsigned c0 = (t2 < NB) ? cnt[t2] : 0;
  unsigned c1 = (t2+1 < NB) ? cnt[t2+1] : 0;
  unsigned pv = c0 + c1, x = pv;
  #pragma unroll
  for (int off=1; off<64; off<<=1){ unsigned u = __shfl_up(x, off); if (lane >= off) x += u; }
  if (lane == 63) wpart[wv] = x;
  __syncthreads();
  unsigned wb = 0;
  #pragma unroll
  for (int q=0;q<4;q++) wb += (q < wv) ? wpart[q] : 0;
  unsigned ex0 = wb + x - pv;
  unsigned ex1 = ex0 + c0;
  if (t2 < NB){
    unsigned gb = c0 ? atomicAdd(&gcursor[t2], c0) : 0u;
    gdst[t2] = gb - ex0;
    cnt[t2]  = ex0;                      // local cursor
  }
  if (t2+1 < NB){
    unsigned gb = c1 ? atomicAdd(&gcursor[t2+1], c1) : 0u;
    gdst[t2+1] = gb - ex1;
    cnt[t2+1]  = ex1;
  }
  __syncthreads();
  // local scatter (bucket-major); stash full dst in hi for phase 4
  #pragma unroll
  for (int i=0;i<16;i++){
    if (dreg[i] < 0) continue;
    int li = tid + 256*i;
    int e = e0 + li;
    int d = dreg[i];
    unsigned pos = atomicAdd(&cnt[d>>7], 1u);
    float tq = fminf(dist[e], 5.f) * ((float)TABN/5.0f);
    int idx = (int)(tq + 0.5f); if (idx > TABN) idx = TABN;   // nearest grid point
    if ((flagbits[e>>5] >> (e&31)) & 1u) idx = TABN+1;        // mask row
    unsigned lo = ((unsigned int)src[e] << 16) | (unsigned int)idx;
    lbuf[pos] = ((unsigned long long)(unsigned int)d << 32) | lo;
  }
  __syncthreads();
  // coalesced write-out
  for (int i=tid; i<m; i+=256){
    unsigned long long v = lbuf[i];
    unsigned d = (unsigned int)(v >> 32);
    unsigned addr = gdst[d>>7] + (unsigned int)i;   // = chunkbase + (i - lexcl)
    bbuf[addr] = (v & 0xFFFFFFFFull) | ((unsigned long long)(d & 127u) << 32);
  }
}

__global__ __launch_bounds__(256) void passB_kernel(const unsigned long long* __restrict__ bbuf,
                                                    const unsigned int* __restrict__ bscan,
                                                    int* __restrict__ offs,
                                                    unsigned int* __restrict__ csr,
                                                    int N){
  __shared__ unsigned int cnt[128];
  __shared__ unsigned int excl[128];
  int b = blockIdx.x, tid = threadIdx.x;
  unsigned int s0 = bscan[b];
  int m = (int)(bscan[b+1] - s0);
  if (tid < 128) cnt[tid] = 0;
  __syncthreads();
  for (int i=tid; i<m; i+=256)
    atomicAdd(&cnt[(unsigned int)(bbuf[s0+i] >> 32)], 1u);
  __syncthreads();
  if (tid < 128) excl[tid] = cnt[tid];
  __syncthreads();
  for (int off=1; off<128; off<<=1){
    unsigned int v = (tid < 128 && tid >= off) ? excl[tid-off] : 0;
    __syncthreads();
    if (tid < 128) excl[tid] += v;
    __syncthreads();
  }
  int node0 = b << 7;
  if (tid < 128){
    unsigned int ex = excl[tid] - cnt[tid];    // exclusive
    int n = node0 + tid;
    if (n < N) offs[n] = (int)(s0 + ex);
    excl[tid] = ex;
    cnt[tid] = 0;                              // reuse as cursor
  }
  __syncthreads();
  for (int i=tid; i<m; i+=256){
    unsigned long long v = bbuf[s0+i];
    unsigned int hi = (unsigned int)(v >> 32);
    unsigned int loc = atomicAdd(&cnt[hi], 1u);
    csr[s0 + excl[hi] + loc] = (unsigned int)v;
  }
}

// ---------------- fused prep: transposes + split weight fragment tables ----------

__global__ void prep_all_kernel(const float* __restrict__ cf_w2,
                                const float* __restrict__ et1_w,
                                const float* __restrict__ nt1_w,
                                const float* __restrict__ cf_w1,
                                const float* __restrict__ cw1,
                                const float* __restrict__ nl2,
                                const float* __restrict__ nl3,
                                float* __restrict__ w2t,
                                float* __restrict__ et1t,
                                float* __restrict__ nt1t,
                                float* __restrict__ w1t,
                                bf16x8* __restrict__ wfrag){
  int id = blockIdx.x*256 + threadIdx.x;
  if (id < 3*4096){
    int i = id >> 12, r = id & 4095;
    int k = r >> 6, j = r & 63;
    w2t[id]  = cf_w2[i*4096 + j*64 + k];
  }
  if (id < 128*64){
    int k = id >> 6, j = id & 63;
    et1t[id] = et1_w[j*128 + k];   // et1_w is [64][128]
  }
  if (id < 64*32){
    int k = id >> 5, j = id & 31;
    nt1t[id] = nt1_w[j*64 + k];    // nt1_w is [32][64]
  }
  if (id < 3*NC*DIM){              // cf_w1 [3][64][50] -> w1t [3][50][64]
    int l = id / (NC*DIM);
    int r = id - l*(NC*DIM);
    int m = r >> 6, k = r & 63;
    w1t[id] = cf_w1[l*DIM*NC + k*NC + m];
  }
  if (id < 9*8*64){                // wfrag: per-lane MFMA B-fragments (hi/lo)
    int lane = id & 63;
    int f8 = (id >> 6) & 7;        // nt*2 + ks
    int m  = id >> 9;
    int nt = f8 >> 1, ks = f8 & 1;
    const float* W = (m < 3) ? (cw1 + m*4096)
                   : (m < 6) ? (nl2 + (m-3)*4096)
                             : (nl3 + (m-6)*4096);
    int j  = nt*16 + (lane & 15);
    int k0 = ks*32 + (lane >> 4)*8;
    bf16x8 vh, vl;
    #pragma unroll
    for (int u=0;u<8;u++){
      unsigned short h,l;
      wsplit(W[j*64 + k0 + u], h, l);
      vh[u] = (short)h; vl[u] = (short)l;
    }
    int fb = m*16 + nt*4 + ks*2;
    wfrag[(fb+0)*64 + lane] = vh;
    wfrag[(fb+1)*64 + lane] = vl;
  }
}

// ---------------- filter table (bf16, nearest), wave = row, lane = feature ----------

__global__ __launch_bounds__(256) void table_kernel(const float* __restrict__ edge_mask,
                                                    const float* __restrict__ w1t,   // [3][50][64]
                                                    const float* __restrict__ cf_b1,
                                                    const float* __restrict__ w2t,   // [3][64][64]
                                                    const float* __restrict__ cf_b2,
                                                    __hip_bfloat16* __restrict__ tabb){
  int row = blockIdx.x*4 + (threadIdx.x >> 6);
  if (row >= 3*TABP) return;
  int l = row / TABP, p = row - l*TABP;
  int lane = threadIdx.x & 63;
  float rbfv = 0.f;
  if (lane < NC){
    if (p == TABN+1) rbfv = edge_mask[lane];
    else {
      float d = (float)p * (5.0f/(float)TABN);
      float c = (lane == NC-1) ? 5.0f : (float)((double)lane * (5.0/49.0));
      float df = d - c;
      rbfv = __expf((float)(-1.0/(5.0/49.0)) * df * df);
    }
  }
  const float* W1 = w1t + l*NC*DIM;
  float t = cf_b1[l*DIM + lane];
  #pragma unroll 10
  for (int m=0;m<NC;m++)
    t = fmaf(rdl(rbfv, m), W1[m*64 + lane], t);
  float su = sp_f(t);
  const float* W2 = w2t + l*DIM*DIM;
  float h = cf_b2[l*DIM + lane];
  #pragma unroll 16
  for (int k=0;k<DIM;k++)
    h = fmaf(rdl(su, k), W2[k*64 + lane], h);
  tabb[((size_t)l*TABP + p)*DIM + lane] = __float2bfloat16(h);
}

// ---------------- node-side v8: MFMA, weights from global fragment tables --------

__device__ __forceinline__ bf16x8 ldfrag(const char* base, int rowbase, int ks, int lane){
  int r = lane & 15;
  int off = (ks<<6) + ((lane>>4)<<4);
  return *(const bf16x8*)(base + (rowbase + r)*128 + (off ^ ((r & 7)<<4)));
}

__device__ __forceinline__ void stx(char* XH, char* XLo, int row, int col, float v){
  unsigned short h,l;
  wsplit(v, h, l);
  int off = row*128 + ((col*2) ^ ((row&7)<<4));
  *(unsigned short*)(XH + off) = h;
  *(unsigned short*)(XLo + off) = l;
}

#define MM6G(WF, NT, ACC) \
  { ACC = MFMA(ah0, (WF)[((NT)*4+0)*64 + lane], ACC); \
    ACC = MFMA(ah1, (WF)[((NT)*4+2)*64 + lane], ACC); \
    ACC = MFMA(ah0, (WF)[((NT)*4+1)*64 + lane], ACC); \
    ACC = MFMA(ah1, (WF)[((NT)*4+3)*64 + lane], ACC); \
    ACC = MFMA(al0, (WF)[((NT)*4+0)*64 + lane], ACC); \
    ACC = MFMA(al1, (WF)[((NT)*4+2)*64 + lane], ACC); }

#define LDA(XH_, XLo_) \
  bf16x8 ah0 = ldfrag(XH_, mb, 0, lane), ah1 = ldfrag(XH_, mb, 1, lane); \
  bf16x8 al0 = ldfrag(XLo_, mb, 0, lane), al1 = ldfrag(XLo_, mb, 1, lane);

// node = emb[node_type]; nnb = bf16(node @ conv_w1[0]^T)
__global__ __launch_bounds__(256) void node_init8_kernel(const float* __restrict__ emb,
                                                         const int* __restrict__ node_type,
                                                         const bf16x8* __restrict__ wf0,
                                                         float* __restrict__ node,
                                                         unsigned short* __restrict__ nout, int N){
  __shared__ __align__(16) char XP[16384];
  char *XH = XP, *XLo = XP + 8192;
  int tid = threadIdx.x, lane = tid & 63, wv = tid >> 6;
  int nb = blockIdx.x*64, mb = wv*16;
  #pragma unroll
  for (int t=0;t<16;t++){
    int row = mb + t, n = nb + row;
    int ty = (n < N) ? node_type[n] : 0;
    float v = emb[(long)ty*64 + lane];
    if (n < N) node[(long)n*64 + lane] = v;
    stx(XH, XLo, row, lane, v);
  }
  __syncthreads();
  LDA(XH, XLo)
  #pragma unroll
  for (int nt=0; nt<4; nt++){
    f32x4 acc = {0.f,0.f,0.f,0.f};
    MM6G(wf0, nt, acc)
    int col = nt*16 + (lane&15);
    #pragma unroll
    for (int v=0; v<4; v++){
      int n = nb + mb + ((lane>>4)<<2) + v;
      if (n < N) nout[(long)n*64 + col] = b16(acc[v]);
    }
  }
}

// node += sp(agg@nl2^T+b2)@nl3^T+b3; optionally nnb = bf16(node_new @ cw1_next^T)
template<bool PRODUCE_NN>
__global__ __launch_bounds__(256) void node_update8_kernel(float* __restrict__ node,
                                                           const float* __restrict__ agg,
                                                           const bf16x8* __restrict__ wfA, // nl2 frags
                                                           const float* __restrict__ nl2_b,
                                                           const bf16x8* __restrict__ wfB, // nl3 frags
                                                           const float* __restrict__ nl3_b,
                                                           const bf16x8* __restrict__ wfC, // cw1_next
                                                           unsigned short* __restrict__ nout, int N){
  __shared__ __align__(16) char XP[16384];
  char *XH = XP, *XLo = XP + 8192;
  int tid = threadIdx.x, lane = tid & 63, wv = tid >> 6;
  int nb = blockIdx.x*64, mb = wv*16;
  // stage agg rows (wave-local)
  #pragma unroll
  for (int t=0;t<16;t++){
    int row = mb + t, n = nb + row;
    float v = (n < N) ? agg[(long)n*64 + lane] : 0.f;
    stx(XH, XLo, row, lane, v);
  }
  __syncthreads();
  // matmul1: S = sp(X @ nl2^T + b2) -> back into X panels (own rows)
  {
    LDA(XH, XLo)
    #pragma unroll
    for (int nt=0; nt<4; nt++){
      float bb = nl2_b[nt*16 + (lane&15)];
      f32x4 acc = {bb,bb,bb,bb};
      MM6G(wfA, nt, acc)
      int col = nt*16 + (lane&15);
      #pragma unroll
      for (int v=0; v<4; v++){
        int row = mb + ((lane>>4)<<2) + v;
        stx(XH, XLo, row, col, sp_f(acc[v]));
      }
    }
  }
  // matmul2: node_new = node + S @ nl3^T + b3 -> node (f32) and X panels
  {
    LDA(XH, XLo)
    #pragma unroll
    for (int nt=0; nt<4; nt++){
      float bb = nl3_b[nt*16 + (lane&15)];
      f32x4 acc = {bb,bb,bb,bb};
      MM6G(wfB, nt, acc)
      int col = nt*16 + (lane&15);
      #pragma unroll
      for (int v=0; v<4; v++){
        int row = mb + ((lane>>4)<<2) + v;
        int n = nb + row;
        float nv = 0.f;
        if (n < N){
          long g = (long)n*64 + col;
          nv = node[g] + acc[v];
          node[g] = nv;
        }
        stx(XH, XLo, row, col, nv);
      }
    }
  }
  if (PRODUCE_NN){
    LDA(XH, XLo)
    #pragma unroll
    for (int nt=0; nt<4; nt++){
      f32x4 acc = {0.f,0.f,0.f,0.f};
      MM6G(wfC, nt, acc)
      int col = nt*16 + (lane&15);
      #pragma unroll
      for (int v=0; v<4; v++){
        int n = nb + mb + ((lane>>4)<<2) + v;
        if (n < N) nout[(long)n*64 + col] = b16(acc[v]);
      }
    }
  }
}

// gather-aggregate v2: wave = 1 dst node (readfirstlane -> SGPR), lane = feature.
__global__ __launch_bounds__(256) void agg_kernel(const unsigned int* __restrict__ csr,
                                                  const int* __restrict__ offs,
                                                  const unsigned short* __restrict__ tab,  // [TABP][64] bf16
                                                  const unsigned short* __restrict__ nnb,  // bf16 bits
                                                  float* __restrict__ agg, int N){
  int n = __builtin_amdgcn_readfirstlane(blockIdx.x*4 + (threadIdx.x >> 6));
  int lane = threadIdx.x & 63;
  if (n >= N) return;
  int beg = offs[n], end = offs[n+1];          // uniform -> s_load
  float acc0 = 0.f, acc1 = 0.f;

#define EDGE(P, ACC) { \
    const unsigned short* tr = tab + (((P) & 0xFFFFu) << 6);   /* SALU ptr math */ \
    const unsigned short* nr = nnb + (((P) >> 16) << 6); \
    float a_  = __uint_as_float(((unsigned int)tr[lane]) << 16); \
    float nn_ = __uint_as_float(((unsigned int)nr[lane]) << 16); \
    ACC = fmaf(nn_, a_, ACC); }

  int c = beg;
  for (; c + 8 <= end; c += 8){
    unsigned p0 = csr[c+0], p1 = csr[c+1], p2 = csr[c+2], p3 = csr[c+3];
    unsigned p4 = csr[c+4], p5 = csr[c+5], p6 = csr[c+6], p7 = csr[c+7];
    EDGE(p0, acc0) EDGE(p1, acc1) EDGE(p2, acc0) EDGE(p3, acc1)
    EDGE(p4, acc0) EDGE(p5, acc1) EDGE(p6, acc0) EDGE(p7, acc1)
  }
  for (; c < end; c++){
    unsigned p = csr[c];
    EDGE(p, acc0)
  }
#undef EDGE
  agg[(long)n*64 + lane] = acc0 + acc1;
}

// ---------------- fused heads ----------------

__global__ __launch_bounds__(256) void heads_kernel(const float* __restrict__ node,
                                                    const int* __restrict__ nidx,
                                                    const float* __restrict__ nt1t,  // [64][32]
                                                    const float* __restrict__ nt1_b,
                                                    const float* __restrict__ nt2_w, // [3][32]
                                                    const float* __restrict__ nt2_b,
                                                    float* __restrict__ outN, int NSEL, int nbN,
                                                    const int* __restrict__ sidx,
                                                    const int* __restrict__ tidx,
                                                    const float* __restrict__ et1t, // [128][64]
                                                    const float* __restrict__ et1_b,
                                                    const float* __restrict__ et2_w,// [5][64]
                                                    const float* __restrict__ et2_b,
                                                    float* __restrict__ outE, int ESEL){
  int lane = threadIdx.x & 63;
  if ((int)blockIdx.x < nbN){
    // ---- node head: wave = 1 row ----
    int r = __builtin_amdgcn_readfirstlane(blockIdx.x*4 + (threadIdx.x>>6));
    if (r >= NSEL) return;
    long n = nidx[r];
    const float* x = node + n*64;                  // uniform -> s_loads
    float u = 0.f;
    if (lane < 32){
      u = nt1_b[lane];
      #pragma unroll
      for (int k=0;k<DIM;k++) u += x[k]*nt1t[k*32 + lane];
    }
    #pragma unroll
    for (int q=0;q<3;q++){
      float v = (lane < 32) ? u*nt2_w[q*32 + lane] : 0.f;
      #pragma unroll
      for (int o=32;o>=1;o>>=1) v += __shfl_xor(v, o);
      if (lane == 0) outN[(long)r*3 + q] = nt2_b[q] + v;
    }
  } else {
    // ---- edge head: wave = 4 rows ----
    int wid = threadIdx.x >> 6;
    int r0 = (((int)blockIdx.x - nbN)*4 + wid)*4;
    if (r0 >= ESEL) return;
    float xs[4], xt[4], acc[4];
    #pragma unroll
    for (int i=0;i<4;i++){
      int r = r0+i < ESEL ? r0+i : ESEL-1;
      long s = sidx[r], t = tidx[r];
      xs[i] = node[s*64 + lane];
      xt[i] = node[t*64 + lane];
      acc[i] = et1_b[lane];
    }
    #pragma unroll 16
    for (int k=0;k<DIM;k++){
      float w1 = et1t[k*64 + lane];
      float w2 = et1t[(64+k)*64 + lane];
      #pragma unroll
      for (int i=0;i<4;i++){
        acc[i] = fmaf(rdl(xs[i], k), w1, acc[i]);
        acc[i] = fmaf(rdl(xt[i], k), w2, acc[i]);
      }
    }
    #pragma unroll
    for (int i=0;i<4;i++){
      if (r0+i >= ESEL) break;
      #pragma unroll
      for (int q=0;q<5;q++){
        float v = acc[i]*et2_w[q*64 + lane];
        #pragma unroll
        for (int o=32;o>=1;o>>=1) v += __shfl_xor(v, o);
        if (lane == 0) outE[(long)(r0+i)*5 + q] = et2_b[q] + v;
      }
    }
  }
}

// ---------------- launch ----------------

extern "C" void kernel_launch(void* const* d_in, const int* in_sizes, int n_in,
                              void* d_out, int out_size, void* d_ws, size_t ws_size,
                              hipStream_t stream){
  const float* emb      = (const float*)d_in[0];
  const float* dist     = (const float*)d_in[1];
  const float* edge_mask= (const float*)d_in[2];
  const float* conv_w1  = (const float*)d_in[3];
  const float* cf_w1    = (const float*)d_in[4];
  const float* cf_b1    = (const float*)d_in[5];
  const float* cf_w2    = (const float*)d_in[6];
  const float* cf_b2    = (const float*)d_in[7];
  const float* nl2_w    = (const float*)d_in[8];
  const float* nl2_b    = (const float*)d_in[9];
  const float* nl3_w    = (const float*)d_in[10];
  const float* nl3_b    = (const float*)d_in[11];
  const float* nt1_w    = (const float*)d_in[12];
  const float* nt1_b    = (const float*)d_in[13];
  const float* nt2_w    = (const float*)d_in[14];
  const float* nt2_b    = (const float*)d_in[15];
  const float* et1_w    = (const float*)d_in[16];
  const float* et1_b    = (const float*)d_in[17];
  const float* et2_w    = (const float*)d_in[18];
  const float* et2_b    = (const float*)d_in[19];
  const int* node_type  = (const int*)d_in[20];
  const int* src        = (const int*)d_in[21];
  const int* dst        = (const int*)d_in[22];
  const int* sel        = (const int*)d_in[23];
  const int* node_index = (const int*)d_in[24];
  const int* source_index = (const int*)d_in[25];
  const int* target_index = (const int*)d_in[26];

  int E    = in_sizes[1];
  int N    = in_sizes[20];
  int K    = in_sizes[23];
  int NSEL = in_sizes[24];
  int ESEL = in_sizes[25];

  int NB  = (N + 127) >> 7;           // buckets of 128 nodes
  int FW  = (E + 31) >> 5;            // flag words
  int nbE = (E + EPB - 1) / EPB;      // CSR-build blocks

  size_t N64 = (size_t)N*64;
  // bbuf (E u64) first for 8B alignment; agg aliases it (lifetimes disjoint)
  unsigned long long* bbuf = (unsigned long long*)d_ws;
  float* agg = (float*)d_ws;
  size_t aggsz = ((size_t)2*E > N64) ? (size_t)2*E : N64;   // float units
  float* p = (float*)d_ws + aggsz;
  float* node     = p; p += N64;
  unsigned short* nnb = (unsigned short*)p; p += N64/2;     // bf16 new_node
  float* w2t      = p; p += 3*4096;
  float* et1t     = p; p += 128*64;
  float* nt1t     = p; p += 64*32;
  float* w1t      = p; p += 3*NC*DIM;
  bf16x8* wfrag   = (bf16x8*)p; p += 9*16*64*4;             // 144KB fragment tables
  __hip_bfloat16* tabb = (__hip_bfloat16*)p; p += (size_t)3*TABP*DIM/2;
  unsigned int* csr      = (unsigned int*)p; p += E;
  unsigned int* gbcnt    = (unsigned int*)p; p += NB;       // adjacent to flagbits:
  unsigned int* flagbits = (unsigned int*)p; p += FW;       //   one memset covers both
  unsigned int* bscan    = (unsigned int*)p; p += NB+1;
  unsigned int* gcursor  = (unsigned int*)p; p += NB;
  int* offs              = (int*)p; p += N+1;

  // CSR build: two-level LDS counting sort
  hipMemsetAsync(gbcnt, 0, (size_t)(NB + FW)*sizeof(int), stream);
  sel_mark_kernel<<<(K+255)/256, 256, 0, stream>>>(sel, flagbits, K);
  bhist_kernel<<<nbE, 256, 0, stream>>>(dst, gbcnt, E, NB);
  prep_all_kernel<<<48, 256, 0, stream>>>(cf_w2, et1_w, nt1_w, cf_w1,
                                          conv_w1, nl2_w, nl3_w,
                                          w2t, et1t, nt1t, w1t, wfrag);
  bscan_kernel<<<1, NBMAX, 0, stream>>>(gbcnt, bscan, gcursor, offs, NB, N, E);
  passA_kernel<<<nbE, 256, 0, stream>>>(dst, src, dist, flagbits, gcursor, bbuf, E, NB);
  passB_kernel<<<NB, 256, 0, stream>>>(bbuf, bscan, offs, csr, N);
  // filter tables (3 layers, wave=row, nearest-neighbor bf16)
  table_kernel<<<(3*TABP+3)/4, 256, 0, stream>>>(edge_mask, w1t, cf_b1, w2t, cf_b2, tabb);

  int nbP  = (N+63)/64;    // node-panel blocks (64 nodes/block, 4 waves)
  int nb_agg = (N+3)/4;    // 4 waves/block x 1 node/wave
  node_init8_kernel<<<nbP, 256, 0, stream>>>(emb, node_type, wfrag, node, nnb, N);
  for (int l=0;l<3;l++){
    agg_kernel<<<nb_agg, 256, 0, stream>>>(csr, offs,
        (const unsigned short*)(tabb + (size_t)l*TABP*DIM), nnb, agg, N);
    if (l < 2)
      node_update8_kernel<true><<<nbP, 256, 0, stream>>>(node, agg,
          wfrag + (3+l)*16*64, nl2_b + l*64,
          wfrag + (6+l)*16*64, nl3_b + l*64,
          wfrag + (1+l)*16*64, nnb, N);
    else
      node_update8_kernel<false><<<nbP, 256, 0, stream>>>(node, agg,
          wfrag + (3+l)*16*64, nl2_b + l*64,
          wfrag + (6+l)*16*64, nl3_b + l*64,
          nullptr, nullptr, N);
  }

  int nbN = (NSEL+3)/4;
  int nbEH = (ESEL+15)/16;
  heads_kernel<<<nbN + nbEH, 256, 0, stream>>>(node, node_index,
      nt1t, nt1_b, nt2_w, nt2_b, (float*)d_out, NSEL, nbN,
      source_index, target_index, et1t, et1_b, et2_w, et2_b,
      (float*)d_out + (size_t)NSEL*3, ESEL);
}